// Round 5
// baseline (1270.453 us; speedup 1.0000x reference)
//
#include <hip/hip_runtime.h>
#include <hip/hip_bf16.h>

typedef __bf16 bf16_t;
typedef __bf16 bf16x4 __attribute__((ext_vector_type(4)));
typedef __bf16 bf16x8 __attribute__((ext_vector_type(8)));
typedef float f32x4 __attribute__((ext_vector_type(4)));
typedef float f32x16 __attribute__((ext_vector_type(16)));

#define NTOK 4096   // B*T
#define TT   512
#define HH   1024
#define VV   32000

#define BM 256
#define BN 256
#define BK 64       // two kh-slices of 32
#define NKT 16      // K-tiles = HH/BK

#define GLOBAL_AS(p) ((const __attribute__((address_space(1))) void*)(const void*)(p))
#define LDS_AS(p)    ((__attribute__((address_space(3))) void*)(void*)(p))

// ---------------------------------------------------------------------------
// f32 -> bf16 bulk convert (memory-bound pre-pass).
// ---------------------------------------------------------------------------
__global__ __launch_bounds__(256)
void grpo_cvt_bf16(const float* __restrict__ src, bf16_t* __restrict__ dst, int n4)
{
    int i = blockIdx.x * 256 + threadIdx.x;
    const int stride = gridDim.x * 256;
    for (; i < n4; i += stride) {
        f32x4 v = *(const f32x4*)(src + (size_t)i * 4);
        bf16x4 b;
#pragma unroll
        for (int e = 0; e < 4; ++e) b[e] = (bf16_t)v[e];
        *(bf16x4*)(dst + (size_t)i * 4) = b;
    }
}

// ---------------------------------------------------------------------------
// 8-phase 256x256 GEMM, 32x32x16 MFMA engine, + logsumexp partial + gather.
// LDS: lds[mat][buf][kh] = 8 regions of [256 rows][32 K] bf16 (16KB each).
// Swizzle: phys 16B slot = logical ^ ((row>>1)&3) (involution; 8 lanes/group
// per b128 wave-read for BOTH the 32-row frag reads and staging => 0 conflict).
// Phase = (buf, kh, k-slice): 4 A-frags + 2 B-frags, 8 MFMA; B never re-read.
// Staging / vmcnt(8) schedule identical to the audited round-4 pipeline.
// ---------------------------------------------------------------------------
template<int SBUF, int SMAT, int SKH>
__device__ __forceinline__ void stage_region(bf16_t* lds0, const bf16_t* __restrict__ g,
                                             int kc, int wid)
{
    bf16_t* reg = lds0 + ((SMAT * 2 + SBUF) * 2 + SKH) * 8192 + wid * 512;
    __builtin_amdgcn_global_load_lds(GLOBAL_AS(g + kc), LDS_AS(reg), 16, 0, 0);
    __builtin_amdgcn_global_load_lds(GLOBAL_AS(g + 128 * HH + kc), LDS_AS(reg + 4096), 16, 0, 0);
}

template<int RBUF, int RKH, int S, int SBUF, int SMAT, int SKH, int SOFF, bool VMW>
__device__ __forceinline__ void phase(bf16_t* lds0, f32x16 (&acc)[4][2],
                                      const bf16_t* lA0, const bf16_t* lA1,
                                      const bf16_t* lB0, const bf16_t* lB1,
                                      const bf16_t* __restrict__ gA,
                                      const bf16_t* __restrict__ gB,
                                      int te, int wid)
{
    const bf16_t* la = S ? lA1 : lA0;
    const bf16_t* lb = S ? lB1 : lB0;

    bf16x8 af[4], bfr[2];
#pragma unroll
    for (int mi = 0; mi < 4; ++mi)
        af[mi] = *(const bf16x8*)(la + (RBUF * 2 + RKH) * 8192 + mi * 1024);
#pragma unroll
    for (int ni = 0; ni < 2; ++ni)
        bfr[ni] = *(const bf16x8*)(lb + (RBUF * 2 + RKH) * 8192 + ni * 1024);

    // prefetch one region for a future K-tile (lands >=5 phases before read)
    {
        const int kc = ((te + SOFF) & (NKT - 1)) * BK + SKH * 32;
        stage_region<SBUF, SMAT, SKH>(lds0, SMAT ? gB : gA, kc, wid);
    }

    asm volatile("s_barrier" ::: "memory");
    asm volatile("s_waitcnt lgkmcnt(0)" ::: "memory");
    __builtin_amdgcn_sched_barrier(0);

    __builtin_amdgcn_s_setprio(1);
#pragma unroll
    for (int mi = 0; mi < 4; ++mi)
#pragma unroll
        for (int ni = 0; ni < 2; ++ni)
            acc[mi][ni] = __builtin_amdgcn_mfma_f32_32x32x16_bf16(
                af[mi], bfr[ni], acc[mi][ni], 0, 0, 0);
    __builtin_amdgcn_s_setprio(0);

    if (VMW) asm volatile("s_waitcnt vmcnt(8)" ::: "memory");  // counted, never 0
    asm volatile("s_barrier" ::: "memory");
}

__global__ __launch_bounds__(512)
void grpo_gemm8(const bf16_t* __restrict__ Xb, const bf16_t* __restrict__ Wb,
                const int* __restrict__ ids,
                float* __restrict__ S, float* __restrict__ SEL)
{
    __shared__ bf16_t lds[2][2][2][256][32];   // [mat][buf][kh], 128 KiB
    bf16_t* lds0 = &lds[0][0][0][0][0];

    const int tid  = threadIdx.x;
    const int lane = tid & 63;
    const int wid  = tid >> 6;
    const int wr   = wid >> 2;          // 0..1 (M split)
    const int wc   = wid & 3;           // 0..3 (N split)
    const int l31  = lane & 31;
    const int hi   = lane >> 5;         // 0/1 : k-half of the fragment
    const int swz  = (l31 >> 1) & 3;    // row-derived XOR (row%32 == l31)

    // lane offsets (elements) within a region for k-slice 0 / 1
    const int loff0 = l31 * 32 + ((hi ^ swz) * 8);
    const int loff1 = loff0 ^ 16;       // phys slot ^= 2

    const bf16_t* lA0 = lds0 + loff0 + wr * 4096;           // A block: regions 0-3
    const bf16_t* lA1 = lds0 + loff1 + wr * 4096;
    const bf16_t* lB0 = lds0 + 32768 + loff0 + wc * 2048;   // B block: regions 4-7
    const bf16_t* lB1 = lds0 + 32768 + loff1 + wc * 2048;

    const int m0 = blockIdx.x * BM;
    const int n0 = blockIdx.y * BN;

    // per-thread staging base pointers (inverse-swizzled source)
    const int srow  = tid >> 2;                       // 0..127
    const int lslot = (tid & 3) ^ ((tid >> 3) & 3);   // involution
    const bf16_t* gA = Xb + (size_t)(m0 + srow) * HH + lslot * 8;
    const bf16_t* gB = Wb + (size_t)(n0 + srow) * HH + lslot * 8;

    f32x16 acc[4][2];
#pragma unroll
    for (int mi = 0; mi < 4; ++mi)
#pragma unroll
        for (int ni = 0; ni < 2; ++ni)
            acc[mi][ni] = (f32x16)0.0f;

    // ---- prologue: tile0 (4 regions) + tile1 kh0 ----
    stage_region<0, 0, 0>(lds0, gA, 0,  wid);
    stage_region<0, 1, 0>(lds0, gB, 0,  wid);
    stage_region<0, 0, 1>(lds0, gA, 32, wid);
    stage_region<0, 1, 1>(lds0, gB, 32, wid);
    stage_region<1, 0, 0>(lds0, gA, 64, wid);
    stage_region<1, 1, 0>(lds0, gB, 64, wid);
    asm volatile("s_waitcnt vmcnt(8)" ::: "memory");   // tile0.kh0 landed
    asm volatile("s_barrier" ::: "memory");

    // ---- main loop: 2 K-tiles per iteration, 8 phases ----
#pragma unroll 1
    for (int it = 0, te = 0; it < NKT / 2; ++it, te += 2) {
        //    <RBUF,RKH,S,  SBUF,SMAT,SKH, SOFF, VMW>
        phase<0, 0, 0,  1, 0, 1,  1, false>(lds0, acc, lA0, lA1, lB0, lB1, gA, gB, te, wid);
        phase<0, 0, 1,  1, 1, 1,  1, true >(lds0, acc, lA0, lA1, lB0, lB1, gA, gB, te, wid);
        phase<0, 1, 0,  0, 0, 0,  2, false>(lds0, acc, lA0, lA1, lB0, lB1, gA, gB, te, wid);
        phase<0, 1, 1,  0, 1, 0,  2, true >(lds0, acc, lA0, lA1, lB0, lB1, gA, gB, te, wid);
        phase<1, 0, 0,  0, 0, 1,  2, false>(lds0, acc, lA0, lA1, lB0, lB1, gA, gB, te, wid);
        phase<1, 0, 1,  0, 1, 1,  2, true >(lds0, acc, lA0, lA1, lB0, lB1, gA, gB, te, wid);
        phase<1, 1, 0,  1, 0, 0,  3, false>(lds0, acc, lA0, lA1, lB0, lB1, gA, gB, te, wid);
        phase<1, 1, 1,  1, 1, 0,  3, true >(lds0, acc, lA0, lA1, lB0, lB1, gA, gB, te, wid);
    }
    asm volatile("s_waitcnt vmcnt(0) lgkmcnt(0)" ::: "memory");
    asm volatile("s_barrier" ::: "memory");

    // ---- epilogue: exp-sum per token row + selected logit ----
    // 32x32 C/D: col = lane&31, row = (rg&3) + 8*(rg>>2) + 4*(lane>>5)
#pragma unroll
    for (int mi = 0; mi < 4; ++mi) {
#pragma unroll
        for (int rg = 0; rg < 16; ++rg) {
            const int row = m0 + wr * 128 + mi * 32 + (rg & 3) + 8 * (rg >> 2) + 4 * hi;
            const float v0 = acc[mi][0][rg];
            const float v1 = acc[mi][1][rg];
            float s = __expf(v0) + __expf(v1);
            s += __shfl_xor(s, 1, 64);
            s += __shfl_xor(s, 2, 64);
            s += __shfl_xor(s, 4, 64);
            s += __shfl_xor(s, 8, 64);
            s += __shfl_xor(s, 16, 64);
            if (l31 == 0) atomicAdd(&S[row], s);

            const int id   = ids[row];
            const int col0 = n0 + wc * 64 + l31;
            if (id == col0)      SEL[row] = v0;
            if (id == col0 + 32) SEL[row] = v1;
        }
    }
}

// ---------------------------------------------------------------------------
// Zero S accumulators (8192 floats).
// ---------------------------------------------------------------------------
__global__ void grpo_init(float* __restrict__ p)
{
    p[blockIdx.x * 1024 + threadIdx.x] = 0.f;
}

// ---------------------------------------------------------------------------
// logp in-place over SEL: lp = SEL - log(S).
// ---------------------------------------------------------------------------
__global__ __launch_bounds__(1024)
void grpo_prep(const float* __restrict__ S_p, const float* __restrict__ S_r,
               float* __restrict__ lp_p, float* __restrict__ lp_r)
{
    int i = blockIdx.x * 1024 + threadIdx.x;
    lp_p[i] = lp_p[i] - logf(S_p[i]);
    lp_r[i] = lp_r[i] - logf(S_r[i]);
}

// ---------------------------------------------------------------------------
// Exact rank-819 threshold (k = int(4096*0.2) = 819), parallel over 64 CUs.
// ---------------------------------------------------------------------------
__global__ __launch_bounds__(64)
void grpo_thresh(const float* __restrict__ lp_r, float* __restrict__ thr)
{
    __shared__ float sh[NTOK];
    for (int i = threadIdx.x; i < NTOK; i += 64) sh[i] = lp_r[i];
    __syncthreads();
    const float v = sh[blockIdx.x * 64 + threadIdx.x];
    int lt = 0, eq = 0;
#pragma unroll 4
    for (int j = 0; j < NTOK; ++j) {
        float u = sh[j];
        lt += (u < v);
        eq += (u == v);
    }
    if (lt <= 818 && 818 < lt + eq) thr[0] = v;
}

// ---------------------------------------------------------------------------
// Final reductions -> 3 scalars. coef_1 == 1 exactly -> ppo = -adv, clip = 0.
// ---------------------------------------------------------------------------
__global__ __launch_bounds__(1024)
void grpo_final(const float* __restrict__ lp_p, const float* __restrict__ lp_r,
                const float* __restrict__ thr,
                const float* __restrict__ am, const float* __restrict__ adv,
                float* __restrict__ out)
{
    __shared__ double red[3][16];
    const int tid = threadIdx.x;
    const float t = thr[0];

    double s_loss = 0.0, s_kl = 0.0, s_am = 0.0;
    for (int i = tid; i < NTOK; i += 1024) {
        float a  = am[i];
        float pr = lp_r[i], pp = lp_p[i];
        float lr = pr - pp;
        float k3 = expf(lr) - lr - 1.0f;
        float kl = (pr <= t) ? k3 * 5.0f : 0.0f;
        float ad = adv[i / TT];
        float ptl = -ad + 0.04f * kl;
        s_loss += (double)(ptl * a);
        s_kl   += (double)(kl * a);
        s_am   += (double)a;
    }
#pragma unroll
    for (int off = 32; off; off >>= 1) {
        s_loss += __shfl_down(s_loss, off, 64);
        s_kl   += __shfl_down(s_kl,   off, 64);
        s_am   += __shfl_down(s_am,   off, 64);
    }
    const int wid = tid >> 6;
    if ((tid & 63) == 0) { red[0][wid] = s_loss; red[1][wid] = s_kl; red[2][wid] = s_am; }
    __syncthreads();
    if (tid == 0) {
        double L = 0, K = 0, A = 0;
        for (int w = 0; w < 16; ++w) { L += red[0][w]; K += red[1][w]; A += red[2][w]; }
        double norm = A < 1.0 ? 1.0 : A;
        out[0] = (float)(L / norm);
        out[1] = (float)(K / norm);
        out[2] = 0.0f;
    }
}

extern "C" void kernel_launch(void* const* d_in, const int* in_sizes, int n_in,
                              void* d_out, int out_size, void* d_ws, size_t ws_size,
                              hipStream_t stream)
{
    const float* X   = (const float*)d_in[0];
    const float* W   = (const float*)d_in[1];
    const int*   ids = (const int*)  d_in[2];
    const float* am  = (const float*)d_in[3];
    const float* adv = (const float*)d_in[4];
    const float* Xr  = (const float*)d_in[5];
    const float* Wr  = (const float*)d_in[6];
    float* out = (float*)d_out;

    float* S_p  = (float*)d_ws;
    float* S_r  = S_p + NTOK;
    float* lp_p = S_r + NTOK;      // SEL_p, overwritten in-place by prep
    float* lp_r = lp_p + NTOK;     // SEL_r
    float* thr  = S_p;             // reused after S consumed

    const size_t bf16_off = 65536;
    const size_t nX = (size_t)NTOK * HH, nW = (size_t)VV * HH;

    bf16_t* Xb  = (bf16_t*)((char*)d_ws + bf16_off);
    bf16_t* Wb  = Xb + nX;
    bf16_t* Xrb = Wb + nW;
    bf16_t* Wrb = Xrb + nX;

    hipLaunchKernelGGL(grpo_init, dim3(8), dim3(1024), 0, stream, S_p);

    hipLaunchKernelGGL(grpo_cvt_bf16, dim3(1024), dim3(256), 0, stream, X,  Xb,  (int)(nX / 4));
    hipLaunchKernelGGL(grpo_cvt_bf16, dim3(2048), dim3(256), 0, stream, W,  Wb,  (int)(nW / 4));
    hipLaunchKernelGGL(grpo_cvt_bf16, dim3(1024), dim3(256), 0, stream, Xr, Xrb, (int)(nX / 4));
    hipLaunchKernelGGL(grpo_cvt_bf16, dim3(2048), dim3(256), 0, stream, Wr, Wrb, (int)(nW / 4));

    dim3 grid(NTOK / BM, VV / BN);   // 16 x 125; m fastest -> W panel L2 reuse
    hipLaunchKernelGGL(grpo_gemm8, grid, dim3(512), 0, stream, Xb,  Wb,  ids, S_p, lp_p);
    hipLaunchKernelGGL(grpo_gemm8, grid, dim3(512), 0, stream, Xrb, Wrb, ids, S_r, lp_r);

    hipLaunchKernelGGL(grpo_prep,   dim3(4),  dim3(1024), 0, stream, S_p, S_r, lp_p, lp_r);
    hipLaunchKernelGGL(grpo_thresh, dim3(64), dim3(64),   0, stream, lp_r, thr);
    hipLaunchKernelGGL(grpo_final,  dim3(1),  dim3(1024), 0, stream, lp_p, lp_r, thr, am, adv, out);
}

// Round 6
// 873.183 us; speedup vs baseline: 1.4550x; 1.4550x over previous
//
#include <hip/hip_runtime.h>
#include <hip/hip_bf16.h>

typedef __bf16 bf16_t;
typedef __bf16 bf16x4 __attribute__((ext_vector_type(4)));
typedef __bf16 bf16x8 __attribute__((ext_vector_type(8)));
typedef float f32x4 __attribute__((ext_vector_type(4)));

#define NTOK 4096   // B*T
#define TT   512
#define HH   1024
#define VV   32000

#define BM 256
#define BN 256
#define BK 64       // two kh-slices of 32
#define NKT 16      // K-tiles = HH/BK

#define GLOBAL_AS(p) ((const __attribute__((address_space(1))) void*)(const void*)(p))
#define LDS_AS(p)    ((__attribute__((address_space(3))) void*)(void*)(p))

// ---------------------------------------------------------------------------
// f32 -> bf16 bulk convert (memory-bound pre-pass).
// ---------------------------------------------------------------------------
__global__ __launch_bounds__(256)
void grpo_cvt_bf16(const float* __restrict__ src, bf16_t* __restrict__ dst, int n4)
{
    int i = blockIdx.x * 256 + threadIdx.x;
    const int stride = gridDim.x * 256;
    for (; i < n4; i += stride) {
        f32x4 v = *(const f32x4*)(src + (size_t)i * 4);
        bf16x4 b;
#pragma unroll
        for (int e = 0; e < 4; ++e) b[e] = (bf16_t)v[e];
        *(bf16x4*)(dst + (size_t)i * 4) = b;
    }
}

// ---------------------------------------------------------------------------
// 8-phase 256x256 GEMM (16x16x32 engine, round-4 mapping: 0 bank conflicts)
// + software-pipelined fragment reads (1 phase ahead, counted lgkmcnt(8))
// + logsumexp partial + selected-logit gather.
// LDS ring: region(b,mat,kh) = [256 rows][32 K] bf16, 16KB; 8 regions, 128KiB.
// Swizzle: phys 16B slot = logical ^ ((row>>1)&3) (involution, measured 0).
// Pipeline audit (per-wave gload queue, 2 ops/region):
//   prologue 12 -> vmcnt(8) lands t0kh0; barrier; frag0 <- t0kh0.
//   vmcnt(6) at EVEN phase ends (pre-barrier) lands exactly the region the
//   following ODD phase top hoists (cross-wave safe: barrier after vmcnt).
//   lgkmcnt(8) waits only the 8 frag reads issued one phase earlier.
//   S(p) != R(p+1) for all p (stage never collides with same-phase hoist).
// ---------------------------------------------------------------------------
template<int SBUF, int SMAT, int SKH>
__device__ __forceinline__ void stage_region(bf16_t* lds0, const bf16_t* __restrict__ src,
                                             int kc, int tid, int wid)
{
    bf16_t* reg = lds0 + ((SBUF * 2 + SMAT) * 2 + SKH) * 8192;
#pragma unroll
    for (int i = 0; i < 2; ++i) {
        const int f     = i * 512 + tid;                  // physical 16B chunk 0..1023
        const int lslot = (f & 3) ^ ((f >> 3) & 3);       // inverse swizzle ((row>>1)&3)
        const bf16_t* g = src + (size_t)(f >> 2) * HH + kc + lslot * 8;
        bf16_t* l = reg + (i * 512 + wid * 64) * 8;       // wave-uniform; HW adds lane*16B
        __builtin_amdgcn_global_load_lds(GLOBAL_AS(g), LDS_AS(l), 16, 0, 0);
    }
}

// load one phase's fragments (A: M-group MG, B: all 4) from region (BUF,KH)
template<int BUF, int KH, int MG>
__device__ __forceinline__ void load_frags(const bf16_t* pA, const bf16_t* pB,
                                           bf16x8 (&a)[4], bf16x8 (&b)[4])
{
    constexpr int ra = ((BUF * 2 + 0) * 2 + KH) * 8192;
    constexpr int rb = ((BUF * 2 + 1) * 2 + KH) * 8192;
#pragma unroll
    for (int m = 0; m < 4; ++m)
        a[m] = *(const bf16x8*)(pA + ra + (MG * 64 + m * 16) * 32);
#pragma unroll
    for (int n = 0; n < 4; ++n)
        b[n] = *(const bf16x8*)(pB + rb + n * 16 * 32);
}

template<int FS, int HBUF, int HKH, int SBUF, int SMAT, int SKH, int SOFF, bool VMW>
__device__ __forceinline__ void phase(f32x4 (&acc)[8][4],
                                      bf16x8 (&fa)[2][4], bf16x8 (&fb)[2][4],
                                      bf16_t* lds0, const bf16_t* pA, const bf16_t* pB,
                                      const bf16_t* __restrict__ gA,
                                      const bf16_t* __restrict__ gB,
                                      int te, int tid, int wid)
{
    // hoist: fragments for phase p+1 (region landed; guaranteed by the
    // vmcnt(6)+barrier at the end of the previous even phase)
    load_frags<HBUF, HKH, FS ^ 1>(pA, pB, fa[FS ^ 1], fb[FS ^ 1]);

    // stage one future region (round-4 schedule)
    {
        const int kc = ((te + SOFF) & (NKT - 1)) * BK + SKH * 32;
        stage_region<SBUF, SMAT, SKH>(lds0, SMAT ? gB : gA, kc, tid, wid);
    }

    // wait only for the 8 frag reads issued one phase ago (counted, never 0)
    asm volatile("s_waitcnt lgkmcnt(8)" ::: "memory");
    __builtin_amdgcn_sched_barrier(0);

    __builtin_amdgcn_s_setprio(1);
#pragma unroll
    for (int m = 0; m < 4; ++m)
#pragma unroll
        for (int n = 0; n < 4; ++n)
            acc[FS * 4 + m][n] = __builtin_amdgcn_mfma_f32_16x16x32_bf16(
                fa[FS][m], fb[FS][n], acc[FS * 4 + m][n], 0, 0, 0);
    __builtin_amdgcn_s_setprio(0);

    if (VMW) asm volatile("s_waitcnt vmcnt(6)" ::: "memory");  // counted, never 0
    asm volatile("s_barrier" ::: "memory");
}

__global__ __launch_bounds__(512)
void grpo_gemm8(const bf16_t* __restrict__ Xb, const bf16_t* __restrict__ Wb,
                const int* __restrict__ ids,
                float* __restrict__ S, float* __restrict__ SEL)
{
    __shared__ bf16_t lds[2][2][2][256][32];   // [buf][mat][kh], 128 KiB
    bf16_t* lds0 = &lds[0][0][0][0][0];

    const int tid  = threadIdx.x;
    const int lane = tid & 63;
    const int wid  = tid >> 6;
    const int wr   = wid >> 2;        // 0..1  (M split)
    const int wc   = wid & 3;         // 0..3  (N split)
    const int l16  = lane & 15;
    const int g    = lane >> 4;                 // logical K-slot
    const int ps   = g ^ ((l16 >> 1) & 3);      // physical (swizzled) K-slot
    // per-lane LDS fragment base pointers (elements)
    const bf16_t* pA = lds0 + (wr * 128 + l16) * 32 + ps * 8;
    const bf16_t* pB = lds0 + (wc * 64 + l16) * 32 + ps * 8;

    const int m0 = blockIdx.x * BM;
    const int n0 = blockIdx.y * BN;

    const bf16_t* gA = Xb + (size_t)m0 * HH;
    const bf16_t* gB = Wb + (size_t)n0 * HH;

    f32x4 acc[8][4];
#pragma unroll
    for (int m = 0; m < 8; ++m)
#pragma unroll
        for (int n = 0; n < 4; ++n)
            acc[m][n] = (f32x4)0.0f;

    bf16x8 fa[2][4], fb[2][4];

    // ---- prologue: tile0 (4 regions) + tile1 kh0; then preload frag set 0 ----
    stage_region<0, 0, 0>(lds0, gA, 0,  tid, wid);
    stage_region<0, 1, 0>(lds0, gB, 0,  tid, wid);
    stage_region<0, 0, 1>(lds0, gA, 32, tid, wid);
    stage_region<0, 1, 1>(lds0, gB, 32, tid, wid);
    stage_region<1, 0, 0>(lds0, gA, 64, tid, wid);
    stage_region<1, 1, 0>(lds0, gB, 64, tid, wid);
    asm volatile("s_waitcnt vmcnt(8)" ::: "memory");   // tile0.kh0 landed
    asm volatile("s_barrier" ::: "memory");            // ...for ALL waves
    load_frags<0, 0, 0>(pA, pB, fa[0], fb[0]);         // P0's fragments

    // ---- main loop: 2 K-tiles / iteration, 8 phases, reads 1 phase ahead ----
#pragma unroll 1
    for (int it = 0, te = 0; it < NKT / 2; ++it, te += 2) {
        //    <FS, H(BUF,KH), S(BUF,MAT,KH), SOFF, VMW>
        phase<0, 0, 0,  1, 0, 1,  1, true >(acc, fa, fb, lds0, pA, pB, gA, gB, te, tid, wid);
        phase<1, 0, 1,  1, 1, 1,  1, false>(acc, fa, fb, lds0, pA, pB, gA, gB, te, tid, wid);
        phase<0, 0, 1,  0, 0, 0,  2, true >(acc, fa, fb, lds0, pA, pB, gA, gB, te, tid, wid);
        phase<1, 1, 0,  0, 1, 0,  2, false>(acc, fa, fb, lds0, pA, pB, gA, gB, te, tid, wid);
        phase<0, 1, 0,  0, 0, 1,  2, true >(acc, fa, fb, lds0, pA, pB, gA, gB, te, tid, wid);
        phase<1, 1, 1,  0, 1, 1,  2, false>(acc, fa, fb, lds0, pA, pB, gA, gB, te, tid, wid);
        phase<0, 1, 1,  1, 0, 0,  3, true >(acc, fa, fb, lds0, pA, pB, gA, gB, te, tid, wid);
        phase<1, 0, 0,  1, 1, 0,  3, false>(acc, fa, fb, lds0, pA, pB, gA, gB, te, tid, wid);
    }
    asm volatile("s_waitcnt vmcnt(0) lgkmcnt(0)" ::: "memory");
    asm volatile("s_barrier" ::: "memory");

    // ---- epilogue: exp-sum per token row + selected logit ----
#pragma unroll
    for (int m = 0; m < 8; ++m) {
#pragma unroll
        for (int j = 0; j < 4; ++j) {
            int row = m0 + wr * 128 + m * 16 + g * 4 + j;
            float s = 0.f;
#pragma unroll
            for (int n = 0; n < 4; ++n)
                s += __expf(acc[m][n][j]);
            s += __shfl_xor(s, 1, 64);
            s += __shfl_xor(s, 2, 64);
            s += __shfl_xor(s, 4, 64);
            s += __shfl_xor(s, 8, 64);
            if (l16 == 0) atomicAdd(&S[row], s);

            int id   = ids[row];
            int base = n0 + wc * 64 + l16;
#pragma unroll
            for (int n = 0; n < 4; ++n)
                if (id == base + n * 16) SEL[row] = acc[m][n][j];
        }
    }
}

// ---------------------------------------------------------------------------
// Zero S accumulators (8192 floats).
// ---------------------------------------------------------------------------
__global__ void grpo_init(float* __restrict__ p)
{
    p[blockIdx.x * 1024 + threadIdx.x] = 0.f;
}

// ---------------------------------------------------------------------------
// logp in-place over SEL: lp = SEL - log(S).
// ---------------------------------------------------------------------------
__global__ __launch_bounds__(1024)
void grpo_prep(const float* __restrict__ S_p, const float* __restrict__ S_r,
               float* __restrict__ lp_p, float* __restrict__ lp_r)
{
    int i = blockIdx.x * 1024 + threadIdx.x;
    lp_p[i] = lp_p[i] - logf(S_p[i]);
    lp_r[i] = lp_r[i] - logf(S_r[i]);
}

// ---------------------------------------------------------------------------
// Exact rank-819 threshold (k = int(4096*0.2) = 819), parallel over 64 CUs.
// ---------------------------------------------------------------------------
__global__ __launch_bounds__(64)
void grpo_thresh(const float* __restrict__ lp_r, float* __restrict__ thr)
{
    __shared__ float sh[NTOK];
    for (int i = threadIdx.x; i < NTOK; i += 64) sh[i] = lp_r[i];
    __syncthreads();
    const float v = sh[blockIdx.x * 64 + threadIdx.x];
    int lt = 0, eq = 0;
#pragma unroll 4
    for (int j = 0; j < NTOK; ++j) {
        float u = sh[j];
        lt += (u < v);
        eq += (u == v);
    }
    if (lt <= 818 && 818 < lt + eq) thr[0] = v;
}

// ---------------------------------------------------------------------------
// Final reductions -> 3 scalars. coef_1 == 1 exactly -> ppo = -adv, clip = 0.
// ---------------------------------------------------------------------------
__global__ __launch_bounds__(1024)
void grpo_final(const float* __restrict__ lp_p, const float* __restrict__ lp_r,
                const float* __restrict__ thr,
                const float* __restrict__ am, const float* __restrict__ adv,
                float* __restrict__ out)
{
    __shared__ double red[3][16];
    const int tid = threadIdx.x;
    const float t = thr[0];

    double s_loss = 0.0, s_kl = 0.0, s_am = 0.0;
    for (int i = tid; i < NTOK; i += 1024) {
        float a  = am[i];
        float pr = lp_r[i], pp = lp_p[i];
        float lr = pr - pp;
        float k3 = expf(lr) - lr - 1.0f;
        float kl = (pr <= t) ? k3 * 5.0f : 0.0f;
        float ad = adv[i / TT];
        float ptl = -ad + 0.04f * kl;
        s_loss += (double)(ptl * a);
        s_kl   += (double)(kl * a);
        s_am   += (double)a;
    }
#pragma unroll
    for (int off = 32; off; off >>= 1) {
        s_loss += __shfl_down(s_loss, off, 64);
        s_kl   += __shfl_down(s_kl,   off, 64);
        s_am   += __shfl_down(s_am,   off, 64);
    }
    const int wid = tid >> 6;
    if ((tid & 63) == 0) { red[0][wid] = s_loss; red[1][wid] = s_kl; red[2][wid] = s_am; }
    __syncthreads();
    if (tid == 0) {
        double L = 0, K = 0, A = 0;
        for (int w = 0; w < 16; ++w) { L += red[0][w]; K += red[1][w]; A += red[2][w]; }
        double norm = A < 1.0 ? 1.0 : A;
        out[0] = (float)(L / norm);
        out[1] = (float)(K / norm);
        out[2] = 0.0f;
    }
}

extern "C" void kernel_launch(void* const* d_in, const int* in_sizes, int n_in,
                              void* d_out, int out_size, void* d_ws, size_t ws_size,
                              hipStream_t stream)
{
    const float* X   = (const float*)d_in[0];
    const float* W   = (const float*)d_in[1];
    const int*   ids = (const int*)  d_in[2];
    const float* am  = (const float*)d_in[3];
    const float* adv = (const float*)d_in[4];
    const float* Xr  = (const float*)d_in[5];
    const float* Wr  = (const float*)d_in[6];
    float* out = (float*)d_out;

    float* S_p  = (float*)d_ws;
    float* S_r  = S_p + NTOK;
    float* lp_p = S_r + NTOK;      // SEL_p, overwritten in-place by prep
    float* lp_r = lp_p + NTOK;     // SEL_r
    float* thr  = S_p;             // reused after S consumed

    const size_t bf16_off = 65536;
    const size_t nX = (size_t)NTOK * HH, nW = (size_t)VV * HH;

    bf16_t* Xb  = (bf16_t*)((char*)d_ws + bf16_off);
    bf16_t* Wb  = Xb + nX;
    bf16_t* Xrb = Wb + nW;
    bf16_t* Wrb = Xrb + nX;

    hipLaunchKernelGGL(grpo_init, dim3(8), dim3(1024), 0, stream, S_p);

    hipLaunchKernelGGL(grpo_cvt_bf16, dim3(1024), dim3(256), 0, stream, X,  Xb,  (int)(nX / 4));
    hipLaunchKernelGGL(grpo_cvt_bf16, dim3(2048), dim3(256), 0, stream, W,  Wb,  (int)(nW / 4));
    hipLaunchKernelGGL(grpo_cvt_bf16, dim3(1024), dim3(256), 0, stream, Xr, Xrb, (int)(nX / 4));
    hipLaunchKernelGGL(grpo_cvt_bf16, dim3(2048), dim3(256), 0, stream, Wr, Wrb, (int)(nW / 4));

    dim3 grid(NTOK / BM, VV / BN);   // 16 x 125; m fastest -> W panel L2 reuse
    hipLaunchKernelGGL(grpo_gemm8, grid, dim3(512), 0, stream, Xb,  Wb,  ids, S_p, lp_p);
    hipLaunchKernelGGL(grpo_gemm8, grid, dim3(512), 0, stream, Xrb, Wrb, ids, S_r, lp_r);

    hipLaunchKernelGGL(grpo_prep,   dim3(4),  dim3(1024), 0, stream, S_p, S_r, lp_p, lp_r);
    hipLaunchKernelGGL(grpo_thresh, dim3(64), dim3(64),   0, stream, lp_r, thr);
    hipLaunchKernelGGL(grpo_final,  dim3(1),  dim3(1024), 0, stream, lp_p, lp_r, thr, am, adv, out);
}

// Round 7
// 856.537 us; speedup vs baseline: 1.4832x; 1.0194x over previous
//
#include <hip/hip_runtime.h>
#include <hip/hip_bf16.h>

typedef __bf16 bf16_t;
typedef __bf16 bf16x4 __attribute__((ext_vector_type(4)));
typedef __bf16 bf16x8 __attribute__((ext_vector_type(8)));
typedef float f32x4 __attribute__((ext_vector_type(4)));

#define NTOK 4096   // B*T
#define TT   512
#define HH   1024
#define VV   32000

#define BM 256
#define BN 256
#define BK 64       // two kh-slices of 32
#define NKT 16      // K-tiles = HH/BK

#define GLOBAL_AS(p) ((const __attribute__((address_space(1))) void*)(const void*)(p))
#define LDS_AS(p)    ((__attribute__((address_space(3))) void*)(void*)(p))

// ---------------------------------------------------------------------------
// f32 -> bf16 bulk convert (memory-bound pre-pass).
// ---------------------------------------------------------------------------
__global__ __launch_bounds__(256)
void grpo_cvt_bf16(const float* __restrict__ src, bf16_t* __restrict__ dst, int n4)
{
    int i = blockIdx.x * 256 + threadIdx.x;
    const int stride = gridDim.x * 256;
    for (; i < n4; i += stride) {
        f32x4 v = *(const f32x4*)(src + (size_t)i * 4);
        bf16x4 b;
#pragma unroll
        for (int e = 0; e < 4; ++e) b[e] = (bf16_t)v[e];
        *(bf16x4*)(dst + (size_t)i * 4) = b;
    }
}

// ---------------------------------------------------------------------------
// 8-phase 256x256 GEMM (16x16x32 engine, 0-conflict swizzle) + B-reg-reuse:
// B fragments are loaded ONCE per (buf,kh) region (odd phases, 8 reads) and
// held in fb[kh] across the region's two M-group phases (even phases: 4 reads,
// A only). LDS read traffic: 64 -> 48 KB/CU/phase. Sync schedule (hoist
// regions, stage order, vmcnt(6) placement, barriers) IDENTICAL to round 6's
// audited pipeline.
// Swizzle: phys 16B slot = logical ^ ((row>>1)&3) (involution, measured 0).
// ---------------------------------------------------------------------------
template<int SBUF, int SMAT, int SKH>
__device__ __forceinline__ void stage_region(bf16_t* lds0, const bf16_t* __restrict__ src,
                                             int kc, int tid, int wid)
{
    bf16_t* reg = lds0 + ((SBUF * 2 + SMAT) * 2 + SKH) * 8192;
#pragma unroll
    for (int i = 0; i < 2; ++i) {
        const int f     = i * 512 + tid;                  // physical 16B chunk 0..1023
        const int lslot = (f & 3) ^ ((f >> 3) & 3);       // inverse swizzle ((row>>1)&3)
        const bf16_t* g = src + (size_t)(f >> 2) * HH + kc + lslot * 8;
        bf16_t* l = reg + (i * 512 + wid * 64) * 8;       // wave-uniform; HW adds lane*16B
        __builtin_amdgcn_global_load_lds(GLOBAL_AS(g), LDS_AS(l), 16, 0, 0);
    }
}

// hoist fragments from region (BUF,KH): A for M-group MG always (4 reads);
// B only when LOADB (4 reads) -> written to b[] (fb[KH] at the call site).
template<int BUF, int KH, int MG, int LOADB>
__device__ __forceinline__ void load_frags(const bf16_t* pA, const bf16_t* pB,
                                           bf16x8 (&a)[4], bf16x8 (&b)[4])
{
    constexpr int ra = ((BUF * 2 + 0) * 2 + KH) * 8192;
    constexpr int rb = ((BUF * 2 + 1) * 2 + KH) * 8192;
#pragma unroll
    for (int m = 0; m < 4; ++m)
        a[m] = *(const bf16x8*)(pA + ra + (MG * 64 + m * 16) * 32);
    if (LOADB) {
#pragma unroll
        for (int n = 0; n < 4; ++n)
            b[n] = *(const bf16x8*)(pB + rb + n * 16 * 32);
    }
}

template<int FS, int RKH, int HBUF, int HKH, int LOADB,
         int SBUF, int SMAT, int SKH, int SOFF, bool VMW, int NLG>
__device__ __forceinline__ void phase(f32x4 (&acc)[8][4],
                                      bf16x8 (&fa)[2][4], bf16x8 (&fb)[2][4],
                                      bf16_t* lds0, const bf16_t* pA, const bf16_t* pB,
                                      const bf16_t* __restrict__ gA,
                                      const bf16_t* __restrict__ gB,
                                      int te, int tid, int wid)
{
    // hoist: A-frags for phase p+1 (M-group FS^1); B-frags only on region entry
    load_frags<HBUF, HKH, FS ^ 1, LOADB>(pA, pB, fa[FS ^ 1], fb[HKH]);

    // stage one future region (round-4/6 schedule, unchanged)
    {
        const int kc = ((te + SOFF) & (NKT - 1)) * BK + SKH * 32;
        stage_region<SBUF, SMAT, SKH>(lds0, SMAT ? gB : gA, kc, tid, wid);
    }

    // wait only for the previous phase's reads (counted: NLG = reads just issued)
    if (NLG == 4) asm volatile("s_waitcnt lgkmcnt(4)" ::: "memory");
    else          asm volatile("s_waitcnt lgkmcnt(8)" ::: "memory");
    __builtin_amdgcn_sched_barrier(0);

    __builtin_amdgcn_s_setprio(1);
#pragma unroll
    for (int m = 0; m < 4; ++m)
#pragma unroll
        for (int n = 0; n < 4; ++n)
            acc[FS * 4 + m][n] = __builtin_amdgcn_mfma_f32_16x16x32_bf16(
                fa[FS][m], fb[RKH][n], acc[FS * 4 + m][n], 0, 0, 0);
    __builtin_amdgcn_s_setprio(0);

    if (VMW) asm volatile("s_waitcnt vmcnt(6)" ::: "memory");  // counted, never 0
    asm volatile("s_barrier" ::: "memory");
}

__global__ __launch_bounds__(512)
void grpo_gemm8(const bf16_t* __restrict__ Xb, const bf16_t* __restrict__ Wb,
                const int* __restrict__ ids,
                float* __restrict__ S, float* __restrict__ SEL)
{
    __shared__ bf16_t lds[2][2][2][256][32];   // [buf][mat][kh], 128 KiB
    bf16_t* lds0 = &lds[0][0][0][0][0];

    const int tid  = threadIdx.x;
    const int lane = tid & 63;
    const int wid  = tid >> 6;
    const int wr   = wid >> 2;        // 0..1  (M split)
    const int wc   = wid & 3;         // 0..3  (N split)
    const int l16  = lane & 15;
    const int g    = lane >> 4;                 // logical K-slot
    const int ps   = g ^ ((l16 >> 1) & 3);      // physical (swizzled) K-slot
    const bf16_t* pA = lds0 + (wr * 128 + l16) * 32 + ps * 8;
    const bf16_t* pB = lds0 + (wc * 64 + l16) * 32 + ps * 8;

    const int m0 = blockIdx.x * BM;
    const int n0 = blockIdx.y * BN;

    const bf16_t* gA = Xb + (size_t)m0 * HH;
    const bf16_t* gB = Wb + (size_t)n0 * HH;

    f32x4 acc[8][4];
#pragma unroll
    for (int m = 0; m < 8; ++m)
#pragma unroll
        for (int n = 0; n < 4; ++n)
            acc[m][n] = (f32x4)0.0f;

    bf16x8 fa[2][4], fb[2][4];

    // ---- prologue: tile0 (4 regions) + tile1 kh0; preload frag set 0 + B(0,0) ----
    stage_region<0, 0, 0>(lds0, gA, 0,  tid, wid);
    stage_region<0, 1, 0>(lds0, gB, 0,  tid, wid);
    stage_region<0, 0, 1>(lds0, gA, 32, tid, wid);
    stage_region<0, 1, 1>(lds0, gB, 32, tid, wid);
    stage_region<1, 0, 0>(lds0, gA, 64, tid, wid);
    stage_region<1, 1, 0>(lds0, gB, 64, tid, wid);
    asm volatile("s_waitcnt vmcnt(8)" ::: "memory");   // tile0.kh0 landed
    asm volatile("s_barrier" ::: "memory");            // ...for ALL waves
    load_frags<0, 0, 0, 1>(pA, pB, fa[0], fb[0]);      // P0's A-frags + region B

    // ---- main loop: 2 K-tiles / iteration, 8 phases, reads 1 phase ahead ----
#pragma unroll 1
    for (int it = 0, te = 0; it < NKT / 2; ++it, te += 2) {
        //    <FS,RKH, H(BUF,KH),LOADB, S(BUF,MAT,KH), SOFF, VMW, NLG>
        phase<0, 0,  0, 0, 0,  1, 0, 1,  1, true,  4>(acc, fa, fb, lds0, pA, pB, gA, gB, te, tid, wid);
        phase<1, 0,  0, 1, 1,  1, 1, 1,  1, false, 8>(acc, fa, fb, lds0, pA, pB, gA, gB, te, tid, wid);
        phase<0, 1,  0, 1, 0,  0, 0, 0,  2, true,  4>(acc, fa, fb, lds0, pA, pB, gA, gB, te, tid, wid);
        phase<1, 1,  1, 0, 1,  0, 1, 0,  2, false, 8>(acc, fa, fb, lds0, pA, pB, gA, gB, te, tid, wid);
        phase<0, 0,  1, 0, 0,  0, 0, 1,  2, true,  4>(acc, fa, fb, lds0, pA, pB, gA, gB, te, tid, wid);
        phase<1, 0,  1, 1, 1,  0, 1, 1,  2, false, 8>(acc, fa, fb, lds0, pA, pB, gA, gB, te, tid, wid);
        phase<0, 1,  1, 1, 0,  1, 0, 0,  3, true,  4>(acc, fa, fb, lds0, pA, pB, gA, gB, te, tid, wid);
        phase<1, 1,  0, 0, 1,  1, 1, 0,  3, false, 8>(acc, fa, fb, lds0, pA, pB, gA, gB, te, tid, wid);
    }
    asm volatile("s_waitcnt vmcnt(0) lgkmcnt(0)" ::: "memory");
    asm volatile("s_barrier" ::: "memory");

    // ---- epilogue: exp-sum per token row + selected logit ----
#pragma unroll
    for (int m = 0; m < 8; ++m) {
#pragma unroll
        for (int j = 0; j < 4; ++j) {
            int row = m0 + wr * 128 + m * 16 + g * 4 + j;
            float s = 0.f;
#pragma unroll
            for (int n = 0; n < 4; ++n)
                s += __expf(acc[m][n][j]);
            s += __shfl_xor(s, 1, 64);
            s += __shfl_xor(s, 2, 64);
            s += __shfl_xor(s, 4, 64);
            s += __shfl_xor(s, 8, 64);
            if (l16 == 0) atomicAdd(&S[row], s);

            int id   = ids[row];
            int base = n0 + wc * 64 + l16;
#pragma unroll
            for (int n = 0; n < 4; ++n)
                if (id == base + n * 16) SEL[row] = acc[m][n][j];
        }
    }
}

// ---------------------------------------------------------------------------
// Zero S accumulators (8192 floats).
// ---------------------------------------------------------------------------
__global__ void grpo_init(float* __restrict__ p)
{
    p[blockIdx.x * 1024 + threadIdx.x] = 0.f;
}

// ---------------------------------------------------------------------------
// logp in-place over SEL: lp = SEL - log(S).
// ---------------------------------------------------------------------------
__global__ __launch_bounds__(1024)
void grpo_prep(const float* __restrict__ S_p, const float* __restrict__ S_r,
               float* __restrict__ lp_p, float* __restrict__ lp_r)
{
    int i = blockIdx.x * 1024 + threadIdx.x;
    lp_p[i] = lp_p[i] - logf(S_p[i]);
    lp_r[i] = lp_r[i] - logf(S_r[i]);
}

// ---------------------------------------------------------------------------
// Exact rank-819 threshold (k = int(4096*0.2) = 819), parallel over 64 CUs.
// ---------------------------------------------------------------------------
__global__ __launch_bounds__(64)
void grpo_thresh(const float* __restrict__ lp_r, float* __restrict__ thr)
{
    __shared__ float sh[NTOK];
    for (int i = threadIdx.x; i < NTOK; i += 64) sh[i] = lp_r[i];
    __syncthreads();
    const float v = sh[blockIdx.x * 64 + threadIdx.x];
    int lt = 0, eq = 0;
#pragma unroll 4
    for (int j = 0; j < NTOK; ++j) {
        float u = sh[j];
        lt += (u < v);
        eq += (u == v);
    }
    if (lt <= 818 && 818 < lt + eq) thr[0] = v;
}

// ---------------------------------------------------------------------------
// Final reductions -> 3 scalars. coef_1 == 1 exactly -> ppo = -adv, clip = 0.
// ---------------------------------------------------------------------------
__global__ __launch_bounds__(1024)
void grpo_final(const float* __restrict__ lp_p, const float* __restrict__ lp_r,
                const float* __restrict__ thr,
                const float* __restrict__ am, const float* __restrict__ adv,
                float* __restrict__ out)
{
    __shared__ double red[3][16];
    const int tid = threadIdx.x;
    const float t = thr[0];

    double s_loss = 0.0, s_kl = 0.0, s_am = 0.0;
    for (int i = tid; i < NTOK; i += 1024) {
        float a  = am[i];
        float pr = lp_r[i], pp = lp_p[i];
        float lr = pr - pp;
        float k3 = expf(lr) - lr - 1.0f;
        float kl = (pr <= t) ? k3 * 5.0f : 0.0f;
        float ad = adv[i / TT];
        float ptl = -ad + 0.04f * kl;
        s_loss += (double)(ptl * a);
        s_kl   += (double)(kl * a);
        s_am   += (double)a;
    }
#pragma unroll
    for (int off = 32; off; off >>= 1) {
        s_loss += __shfl_down(s_loss, off, 64);
        s_kl   += __shfl_down(s_kl,   off, 64);
        s_am   += __shfl_down(s_am,   off, 64);
    }
    const int wid = tid >> 6;
    if ((tid & 63) == 0) { red[0][wid] = s_loss; red[1][wid] = s_kl; red[2][wid] = s_am; }
    __syncthreads();
    if (tid == 0) {
        double L = 0, K = 0, A = 0;
        for (int w = 0; w < 16; ++w) { L += red[0][w]; K += red[1][w]; A += red[2][w]; }
        double norm = A < 1.0 ? 1.0 : A;
        out[0] = (float)(L / norm);
        out[1] = (float)(K / norm);
        out[2] = 0.0f;
    }
}

extern "C" void kernel_launch(void* const* d_in, const int* in_sizes, int n_in,
                              void* d_out, int out_size, void* d_ws, size_t ws_size,
                              hipStream_t stream)
{
    const float* X   = (const float*)d_in[0];
    const float* W   = (const float*)d_in[1];
    const int*   ids = (const int*)  d_in[2];
    const float* am  = (const float*)d_in[3];
    const float* adv = (const float*)d_in[4];
    const float* Xr  = (const float*)d_in[5];
    const float* Wr  = (const float*)d_in[6];
    float* out = (float*)d_out;

    float* S_p  = (float*)d_ws;
    float* S_r  = S_p + NTOK;
    float* lp_p = S_r + NTOK;      // SEL_p, overwritten in-place by prep
    float* lp_r = lp_p + NTOK;     // SEL_r
    float* thr  = S_p;             // reused after S consumed

    const size_t bf16_off = 65536;
    const size_t nX = (size_t)NTOK * HH, nW = (size_t)VV * HH;

    bf16_t* Xb  = (bf16_t*)((char*)d_ws + bf16_off);
    bf16_t* Wb  = Xb + nX;
    bf16_t* Xrb = Wb + nW;
    bf16_t* Wrb = Xrb + nX;

    hipLaunchKernelGGL(grpo_init, dim3(8), dim3(1024), 0, stream, S_p);

    hipLaunchKernelGGL(grpo_cvt_bf16, dim3(1024), dim3(256), 0, stream, X,  Xb,  (int)(nX / 4));
    hipLaunchKernelGGL(grpo_cvt_bf16, dim3(2048), dim3(256), 0, stream, W,  Wb,  (int)(nW / 4));
    hipLaunchKernelGGL(grpo_cvt_bf16, dim3(1024), dim3(256), 0, stream, Xr, Xrb, (int)(nX / 4));
    hipLaunchKernelGGL(grpo_cvt_bf16, dim3(2048), dim3(256), 0, stream, Wr, Wrb, (int)(nW / 4));

    dim3 grid(NTOK / BM, VV / BN);   // 16 x 125; m fastest -> W panel L2 reuse
    hipLaunchKernelGGL(grpo_gemm8, grid, dim3(512), 0, stream, Xb,  Wb,  ids, S_p, lp_p);
    hipLaunchKernelGGL(grpo_gemm8, grid, dim3(512), 0, stream, Xrb, Wrb, ids, S_r, lp_r);

    hipLaunchKernelGGL(grpo_prep,   dim3(4),  dim3(1024), 0, stream, S_p, S_r, lp_p, lp_r);
    hipLaunchKernelGGL(grpo_thresh, dim3(64), dim3(64),   0, stream, lp_r, thr);
    hipLaunchKernelGGL(grpo_final,  dim3(1),  dim3(1024), 0, stream, lp_p, lp_r, thr, am, adv, out);
}

// Round 8
// 837.091 us; speedup vs baseline: 1.5177x; 1.0232x over previous
//
#include <hip/hip_runtime.h>
#include <hip/hip_bf16.h>

typedef __bf16 bf16_t;
typedef __bf16 bf16x4 __attribute__((ext_vector_type(4)));
typedef __bf16 bf16x8 __attribute__((ext_vector_type(8)));
typedef float f32x4 __attribute__((ext_vector_type(4)));

#define NTOK 4096   // B*T
#define TT   512
#define HH   1024
#define VV   32000

#define BM 256
#define BN 256
#define BK 64       // two kh-slices of 32
#define NKT 16      // K-tiles = HH/BK

#define GLOBAL_AS(p) ((const __attribute__((address_space(1))) void*)(const void*)(p))
#define LDS_AS(p)    ((__attribute__((address_space(3))) void*)(void*)(p))

// ---------------------------------------------------------------------------
// f32 -> bf16 bulk convert, all four tensors in one dispatch (memory-bound).
// ---------------------------------------------------------------------------
__global__ __launch_bounds__(256)
void grpo_cvt_all(const float* __restrict__ X,  const float* __restrict__ W,
                  const float* __restrict__ Xr, const float* __restrict__ Wr,
                  bf16_t* __restrict__ Xb,  bf16_t* __restrict__ Wb,
                  bf16_t* __restrict__ Xrb, bf16_t* __restrict__ Wrb)
{
    const int nX4 = NTOK * HH / 4;        // 1,048,576
    const int nW4 = VV * HH / 4;          // 8,192,000
    const int b1 = nX4, b2 = nX4 + nW4, b3 = nX4 + nW4 + nX4;
    const int total = 2 * (nX4 + nW4);
    const int stride = gridDim.x * 256;
    for (int i = blockIdx.x * 256 + threadIdx.x; i < total; i += stride) {
        const float* s; bf16_t* d; int j;
        if      (i < b1) { s = X;  d = Xb;  j = i; }
        else if (i < b2) { s = W;  d = Wb;  j = i - b1; }
        else if (i < b3) { s = Xr; d = Xrb; j = i - b2; }
        else             { s = Wr; d = Wrb; j = i - b3; }
        f32x4 v = *(const f32x4*)(s + (size_t)j * 4);
        bf16x4 b;
#pragma unroll
        for (int e = 0; e < 4; ++e) b[e] = (bf16_t)v[e];
        *(bf16x4*)(d + (size_t)j * 4) = b;
    }
}

// ---------------------------------------------------------------------------
// 4-phase 256x256 GEMM (16x16x32 engine, 0-conflict swizzle), z-merged
// policy/ref, + logsumexp partial + selected-logit gather.
// LDS ring: region(buf,mat,kh) = [256 rows][32 K] bf16, 16KB; 8 regions 128KiB.
// Swizzle: phys 16B slot = logical ^ ((row>>1)&3) (involution, measured 0).
//
// Phase = one (buf,kh) region: 12 ds_read (A m0..7 + B n0..3), stage one A+B
// region pair (4 gload_lds), lgkmcnt(0)+sched_barrier, 32 MFMA, vmcnt(4),
// barrier. Ring audit:
//   P0 read(0,kh0)  stage pair(1,kh1)<-T+1   (pair last read prev-P3, WAR ok)
//   P1 read(0,kh1)  stage pair(0,kh0)<-T+2   (last read P0)
//   P2 read(1,kh0)  stage pair(0,kh1)<-T+2   (last read P1)
//   P3 read(1,kh1)  stage pair(1,kh0)<-T+3   (last read P2)
// vmcnt(4) each phase end => the previous phase's 4 loads have landed, which
// is always >=1 phase before any reader. Prologue: 6 regions, vmcnt(8).
// ---------------------------------------------------------------------------
template<int SBUF, int SMAT, int SKH>
__device__ __forceinline__ void stage_region(bf16_t* lds0, const bf16_t* __restrict__ src,
                                             int kc, int tid, int wid)
{
    bf16_t* reg = lds0 + ((SBUF * 2 + SMAT) * 2 + SKH) * 8192;
#pragma unroll
    for (int i = 0; i < 2; ++i) {
        const int f     = i * 512 + tid;                  // physical 16B chunk 0..1023
        const int lslot = (f & 3) ^ ((f >> 3) & 3);       // inverse swizzle ((row>>1)&3)
        const bf16_t* g = src + (size_t)(f >> 2) * HH + kc + lslot * 8;
        bf16_t* l = reg + (i * 512 + wid * 64) * 8;       // wave-uniform; HW adds lane*16B
        __builtin_amdgcn_global_load_lds(GLOBAL_AS(g), LDS_AS(l), 16, 0, 0);
    }
}

template<int RBUF, int RKH, int SBUF, int SKH, int SOFF>
__device__ __forceinline__ void phase(f32x4 (&acc)[8][4], bf16_t* lds0,
                                      const bf16_t* pA, const bf16_t* pB,
                                      const bf16_t* __restrict__ gA,
                                      const bf16_t* __restrict__ gB,
                                      int te, int tid, int wid)
{
    constexpr int ra = ((RBUF * 2 + 0) * 2 + RKH) * 8192;
    constexpr int rb = ((RBUF * 2 + 1) * 2 + RKH) * 8192;

    bf16x8 fa[8], fb[4];
#pragma unroll
    for (int m = 0; m < 8; ++m)
        fa[m] = *(const bf16x8*)(pA + ra + m * 16 * 32);
#pragma unroll
    for (int n = 0; n < 4; ++n)
        fb[n] = *(const bf16x8*)(pB + rb + n * 16 * 32);

    // stage one future A+B region pair (ring schedule above)
    {
        const int kc = ((te + SOFF) & (NKT - 1)) * BK + SKH * 32;
        stage_region<SBUF, 0, SKH>(lds0, gA, kc, tid, wid);
        stage_region<SBUF, 1, SKH>(lds0, gB, kc, tid, wid);
    }

    asm volatile("s_waitcnt lgkmcnt(0)" ::: "memory");   // this phase's 12 reads
    __builtin_amdgcn_sched_barrier(0);

    __builtin_amdgcn_s_setprio(1);
#pragma unroll
    for (int m = 0; m < 8; ++m)
#pragma unroll
        for (int n = 0; n < 4; ++n)
            acc[m][n] = __builtin_amdgcn_mfma_f32_16x16x32_bf16(
                fa[m], fb[n], acc[m][n], 0, 0, 0);
    __builtin_amdgcn_s_setprio(0);

    asm volatile("s_waitcnt vmcnt(4)" ::: "memory");     // counted, never 0
    asm volatile("s_barrier" ::: "memory");
}

__global__ __launch_bounds__(512)
void grpo_gemm4(const bf16_t* __restrict__ Xb,  const bf16_t* __restrict__ Wb,
                const bf16_t* __restrict__ Xrb, const bf16_t* __restrict__ Wrb,
                const int* __restrict__ ids,
                float* __restrict__ S_p, float* __restrict__ SEL_p,
                float* __restrict__ S_r, float* __restrict__ SEL_r)
{
    __shared__ bf16_t lds[2][2][2][256][32];   // [buf][mat][kh], 128 KiB
    bf16_t* lds0 = &lds[0][0][0][0][0];

    const int tid  = threadIdx.x;
    const int lane = tid & 63;
    const int wid  = tid >> 6;
    const int wr   = wid >> 2;        // 0..1  (M split)
    const int wc   = wid & 3;         // 0..3  (N split)
    const int l16  = lane & 15;
    const int g    = lane >> 4;                 // logical K-slot
    const int ps   = g ^ ((l16 >> 1) & 3);      // physical (swizzled) K-slot
    const bf16_t* pA = lds0 + (wr * 128 + l16) * 32 + ps * 8;
    const bf16_t* pB = lds0 + (wc * 64 + l16) * 32 + ps * 8;

    const int zz = blockIdx.z;                  // 0 = policy, 1 = ref
    const bf16_t* Xs = zz ? Xrb : Xb;
    const bf16_t* Ws = zz ? Wrb : Wb;
    float* S   = zz ? S_r   : S_p;
    float* SEL = zz ? SEL_r : SEL_p;

    const int m0 = blockIdx.x * BM;
    const int n0 = blockIdx.y * BN;

    const bf16_t* gA = Xs + (size_t)m0 * HH;
    const bf16_t* gB = Ws + (size_t)n0 * HH;

    f32x4 acc[8][4];
#pragma unroll
    for (int m = 0; m < 8; ++m)
#pragma unroll
        for (int n = 0; n < 4; ++n)
            acc[m][n] = (f32x4)0.0f;

    // ---- prologue: tile0 (both kh) + tile1 kh0 = 6 regions, 12 loads/wave ----
    stage_region<0, 0, 0>(lds0, gA, 0,  tid, wid);
    stage_region<0, 1, 0>(lds0, gB, 0,  tid, wid);
    stage_region<0, 0, 1>(lds0, gA, 32, tid, wid);
    stage_region<0, 1, 1>(lds0, gB, 32, tid, wid);
    stage_region<1, 0, 0>(lds0, gA, 64, tid, wid);
    stage_region<1, 1, 0>(lds0, gB, 64, tid, wid);
    asm volatile("s_waitcnt vmcnt(8)" ::: "memory");   // tile0.kh0 landed
    asm volatile("s_barrier" ::: "memory");

    // ---- main loop: 2 K-tiles / iteration, 4 fat phases ----
#pragma unroll 1
    for (int it = 0, te = 0; it < NKT / 2; ++it, te += 2) {
        //    <R(BUF,KH), S(BUF,KH), SOFF>
        phase<0, 0,  1, 1,  1>(acc, lds0, pA, pB, gA, gB, te, tid, wid);
        phase<0, 1,  0, 0,  2>(acc, lds0, pA, pB, gA, gB, te, tid, wid);
        phase<1, 0,  0, 1,  2>(acc, lds0, pA, pB, gA, gB, te, tid, wid);
        phase<1, 1,  1, 0,  3>(acc, lds0, pA, pB, gA, gB, te, tid, wid);
    }
    asm volatile("s_waitcnt vmcnt(0) lgkmcnt(0)" ::: "memory");
    asm volatile("s_barrier" ::: "memory");

    // ---- epilogue: exp-sum per token row + selected logit ----
#pragma unroll
    for (int m = 0; m < 8; ++m) {
#pragma unroll
        for (int j = 0; j < 4; ++j) {
            int row = m0 + wr * 128 + m * 16 + g * 4 + j;
            float s = 0.f;
#pragma unroll
            for (int n = 0; n < 4; ++n)
                s += __expf(acc[m][n][j]);
            s += __shfl_xor(s, 1, 64);
            s += __shfl_xor(s, 2, 64);
            s += __shfl_xor(s, 4, 64);
            s += __shfl_xor(s, 8, 64);
            if (l16 == 0) atomicAdd(&S[row], s);

            int id   = ids[row];
            int base = n0 + wc * 64 + l16;
#pragma unroll
            for (int n = 0; n < 4; ++n)
                if (id == base + n * 16) SEL[row] = acc[m][n][j];
        }
    }
}

// ---------------------------------------------------------------------------
// Zero S accumulators (8192 floats).
// ---------------------------------------------------------------------------
__global__ void grpo_init(float* __restrict__ p)
{
    p[blockIdx.x * 1024 + threadIdx.x] = 0.f;
}

// ---------------------------------------------------------------------------
// logp in-place over SEL: lp = SEL - log(S).
// ---------------------------------------------------------------------------
__global__ __launch_bounds__(1024)
void grpo_prep(const float* __restrict__ S_p, const float* __restrict__ S_r,
               float* __restrict__ lp_p, float* __restrict__ lp_r)
{
    int i = blockIdx.x * 1024 + threadIdx.x;
    lp_p[i] = lp_p[i] - logf(S_p[i]);
    lp_r[i] = lp_r[i] - logf(S_r[i]);
}

// ---------------------------------------------------------------------------
// Exact rank-819 threshold (k = int(4096*0.2) = 819), parallel over 64 CUs.
// ---------------------------------------------------------------------------
__global__ __launch_bounds__(64)
void grpo_thresh(const float* __restrict__ lp_r, float* __restrict__ thr)
{
    __shared__ float sh[NTOK];
    for (int i = threadIdx.x; i < NTOK; i += 64) sh[i] = lp_r[i];
    __syncthreads();
    const float v = sh[blockIdx.x * 64 + threadIdx.x];
    int lt = 0, eq = 0;
#pragma unroll 4
    for (int j = 0; j < NTOK; ++j) {
        float u = sh[j];
        lt += (u < v);
        eq += (u == v);
    }
    if (lt <= 818 && 818 < lt + eq) thr[0] = v;
}

// ---------------------------------------------------------------------------
// Final reductions -> 3 scalars. coef_1 == 1 exactly -> ppo = -adv, clip = 0.
// ---------------------------------------------------------------------------
__global__ __launch_bounds__(1024)
void grpo_final(const float* __restrict__ lp_p, const float* __restrict__ lp_r,
                const float* __restrict__ thr,
                const float* __restrict__ am, const float* __restrict__ adv,
                float* __restrict__ out)
{
    __shared__ double red[3][16];
    const int tid = threadIdx.x;
    const float t = thr[0];

    double s_loss = 0.0, s_kl = 0.0, s_am = 0.0;
    for (int i = tid; i < NTOK; i += 1024) {
        float a  = am[i];
        float pr = lp_r[i], pp = lp_p[i];
        float lr = pr - pp;
        float k3 = expf(lr) - lr - 1.0f;
        float kl = (pr <= t) ? k3 * 5.0f : 0.0f;
        float ad = adv[i / TT];
        float ptl = -ad + 0.04f * kl;
        s_loss += (double)(ptl * a);
        s_kl   += (double)(kl * a);
        s_am   += (double)a;
    }
#pragma unroll
    for (int off = 32; off; off >>= 1) {
        s_loss += __shfl_down(s_loss, off, 64);
        s_kl   += __shfl_down(s_kl,   off, 64);
        s_am   += __shfl_down(s_am,   off, 64);
    }
    const int wid = tid >> 6;
    if ((tid & 63) == 0) { red[0][wid] = s_loss; red[1][wid] = s_kl; red[2][wid] = s_am; }
    __syncthreads();
    if (tid == 0) {
        double L = 0, K = 0, A = 0;
        for (int w = 0; w < 16; ++w) { L += red[0][w]; K += red[1][w]; A += red[2][w]; }
        double norm = A < 1.0 ? 1.0 : A;
        out[0] = (float)(L / norm);
        out[1] = (float)(K / norm);
        out[2] = 0.0f;
    }
}

extern "C" void kernel_launch(void* const* d_in, const int* in_sizes, int n_in,
                              void* d_out, int out_size, void* d_ws, size_t ws_size,
                              hipStream_t stream)
{
    const float* X   = (const float*)d_in[0];
    const float* W   = (const float*)d_in[1];
    const int*   ids = (const int*)  d_in[2];
    const float* am  = (const float*)d_in[3];
    const float* adv = (const float*)d_in[4];
    const float* Xr  = (const float*)d_in[5];
    const float* Wr  = (const float*)d_in[6];
    float* out = (float*)d_out;

    float* S_p  = (float*)d_ws;
    float* S_r  = S_p + NTOK;
    float* lp_p = S_r + NTOK;      // SEL_p, overwritten in-place by prep
    float* lp_r = lp_p + NTOK;     // SEL_r
    float* thr  = S_p;             // reused after S consumed

    const size_t bf16_off = 65536;
    const size_t nX = (size_t)NTOK * HH, nW = (size_t)VV * HH;

    bf16_t* Xb  = (bf16_t*)((char*)d_ws + bf16_off);
    bf16_t* Wb  = Xb + nX;
    bf16_t* Xrb = Wb + nW;
    bf16_t* Wrb = Xrb + nX;

    hipLaunchKernelGGL(grpo_init, dim3(8), dim3(1024), 0, stream, S_p);

    hipLaunchKernelGGL(grpo_cvt_all, dim3(4096), dim3(256), 0, stream,
                       X, W, Xr, Wr, Xb, Wb, Xrb, Wrb);

    dim3 grid(NTOK / BM, VV / BN, 2);   // m fastest; z = policy/ref
    hipLaunchKernelGGL(grpo_gemm4, grid, dim3(512), 0, stream,
                       Xb, Wb, Xrb, Wrb, ids, S_p, lp_p, S_r, lp_r);

    hipLaunchKernelGGL(grpo_prep,   dim3(4),  dim3(1024), 0, stream, S_p, S_r, lp_p, lp_r);
    hipLaunchKernelGGL(grpo_thresh, dim3(64), dim3(64),   0, stream, lp_r, thr);
    hipLaunchKernelGGL(grpo_final,  dim3(1),  dim3(1024), 0, stream, lp_p, lp_r, thr, am, adv, out);
}

// Round 9
// 836.037 us; speedup vs baseline: 1.5196x; 1.0013x over previous
//
#include <hip/hip_runtime.h>
#include <hip/hip_bf16.h>

typedef __bf16 bf16_t;
typedef __bf16 bf16x4 __attribute__((ext_vector_type(4)));
typedef __bf16 bf16x8 __attribute__((ext_vector_type(8)));
typedef float f32x4 __attribute__((ext_vector_type(4)));

#define NTOK 4096   // B*T
#define TT   512
#define HH   1024
#define VV   32000

#define BM 256
#define BN 256
#define BK 64
#define NKT 16      // K-tiles = HH/BK

#define GLOBAL_AS(p) ((const __attribute__((address_space(1))) void*)(const void*)(p))
#define LDS_AS(p)    ((__attribute__((address_space(3))) void*)(void*)(p))

#define BAR()   asm volatile("s_barrier" ::: "memory")
#define LGKM0() asm volatile("s_waitcnt lgkmcnt(0)" ::: "memory")
#define VM4()   asm volatile("s_waitcnt vmcnt(4)" ::: "memory")
#define SB0()   __builtin_amdgcn_sched_barrier(0)

// ---------------------------------------------------------------------------
// f32 -> bf16 bulk convert, all four tensors in one dispatch (memory-bound).
// ---------------------------------------------------------------------------
__global__ __launch_bounds__(256)
void grpo_cvt_all(const float* __restrict__ X,  const float* __restrict__ W,
                  const float* __restrict__ Xr, const float* __restrict__ Wr,
                  bf16_t* __restrict__ Xb,  bf16_t* __restrict__ Wb,
                  bf16_t* __restrict__ Xrb, bf16_t* __restrict__ Wrb)
{
    const int nX4 = NTOK * HH / 4;
    const int nW4 = VV * HH / 4;
    const int b1 = nX4, b2 = nX4 + nW4, b3 = nX4 + nW4 + nX4;
    const int total = 2 * (nX4 + nW4);
    const int stride = gridDim.x * 256;
    for (int i = blockIdx.x * 256 + threadIdx.x; i < total; i += stride) {
        const float* s; bf16_t* d; int j;
        if      (i < b1) { s = X;  d = Xb;  j = i; }
        else if (i < b2) { s = W;  d = Wb;  j = i - b1; }
        else if (i < b3) { s = Xr; d = Xrb; j = i - b2; }
        else             { s = Wr; d = Wrb; j = i - b3; }
        f32x4 v = *(const f32x4*)(s + (size_t)j * 4);
        bf16x4 b;
#pragma unroll
        for (int e = 0; e < 4; ++e) b[e] = (bf16_t)v[e];
        *(bf16x4*)(d + (size_t)j * 4) = b;
    }
}

// ---------------------------------------------------------------------------
// m201-template 256x256 GEMM port: 8 phases/iter (2 K-tiles of BK=64),
// 16 MFMA/phase, B-in-registers per K-tile, reads issued BEFORE the
// convergence barrier, vmcnt(4) only at P4/P8.  z-merged policy/ref.
// LDS: 8 regions of [128 rows][64 K] bf16 (16KB): idx = buf*4 + mat*2 + half.
// Swizzle: phys 16B slot = logical ^ (row&7) (involution; ds_read 2-way=free;
// staging inverse-swizzles the global source, linear LDS dest).
//
// Staging ledger (per iter, tiles t=buf0, t+1=buf1; 2 gloads per half-tile):
//   P1: Ab1h0<-t+1 | P2: Ab1h1<-t+1, Bb0h0<-t+2 | P3: Bb0h1<-t+2 | P4: -
//   P5: Ab0h0<-t+2 | P6: Ab0h1<-t+2, Bb1h0<-t+3 | P7: Bb1h1<-t+3 | P8: -
//   vmcnt(4)@P4 keeps {Bb0} -> drains {Bb1_prev, Ab1} before their P5 reads.
//   vmcnt(4)@P8 keeps {Bb1} -> drains {Bb0, Ab0} before next-iter P1 reads.
//   All WAR: region re-staged >=1 phase after last read (issue follows the
//   reader's lgkm(0) + end barrier), so async DMA landing cannot precede it.
// Prologue: Bb0h0,Bb0h1,Ab0h0,Ab0h1 (t0), Bb1h0,Bb1h1 (t1); vmcnt(4) ->
//   t0 landed, carry = Bb1 (the steady-state carry).
// ---------------------------------------------------------------------------
template<int BUF, int MAT, int HALF>
__device__ __forceinline__ void stage_half(bf16_t* lds0, const bf16_t* __restrict__ src,
                                           int kc, int tid, int wid)
{
    bf16_t* reg = lds0 + (BUF * 4 + MAT * 2 + HALF) * 8192;
#pragma unroll
    for (int i = 0; i < 2; ++i) {
        const int f     = i * 512 + tid;              // phys 16B chunk 0..1023
        const int row   = f >> 3;                     // 0..127
        const int lslot = (f & 7) ^ (row & 7);        // inverse swizzle
        const bf16_t* g = src + (size_t)(HALF * 128 + row) * HH + kc + lslot * 8;
        bf16_t* l = reg + (i * 512 + wid * 64) * 8;   // wave-uniform; HW adds lane*16B
        __builtin_amdgcn_global_load_lds(GLOBAL_AS(g), LDS_AS(l), 16, 0, 0);
    }
}

template<int BUF>
__device__ __forceinline__ void read_b(const bf16_t* pbk0, const bf16_t* pbk1,
                                       bf16x8 (&bq)[2][4])
{
#pragma unroll
    for (int n = 0; n < 4; ++n) {
        bq[0][n] = *(const bf16x8*)(pbk0 + BUF * 32768 + n * 1024);
        bq[1][n] = *(const bf16x8*)(pbk1 + BUF * 32768 + n * 1024);
    }
}

template<int BUF, int MP>
__device__ __forceinline__ void read_a(const bf16_t* pak0, const bf16_t* pak1,
                                       bf16x8 (&aq)[2][2])
{
#pragma unroll
    for (int i = 0; i < 2; ++i) {
        aq[0][i] = *(const bf16x8*)(pak0 + BUF * 32768 + (MP * 2 + i) * 1024);
        aq[1][i] = *(const bf16x8*)(pak1 + BUF * 32768 + (MP * 2 + i) * 1024);
    }
}

template<int MP>
__device__ __forceinline__ void mfma16(f32x4 (&acc)[8][4],
                                       bf16x8 (&aq)[2][2], bf16x8 (&bq)[2][4])
{
#pragma unroll
    for (int kh = 0; kh < 2; ++kh)
#pragma unroll
        for (int i = 0; i < 2; ++i)
#pragma unroll
            for (int n = 0; n < 4; ++n)
                acc[MP * 2 + i][n] = __builtin_amdgcn_mfma_f32_16x16x32_bf16(
                    aq[kh][i], bq[kh][n], acc[MP * 2 + i][n], 0, 0, 0);
}

__global__ __launch_bounds__(512)
void grpo_gemm_t(const bf16_t* __restrict__ Xb,  const bf16_t* __restrict__ Wb,
                 const bf16_t* __restrict__ Xrb, const bf16_t* __restrict__ Wrb,
                 const int* __restrict__ ids,
                 float* __restrict__ S_p, float* __restrict__ SEL_p,
                 float* __restrict__ S_r, float* __restrict__ SEL_r)
{
    __shared__ bf16_t lds[8][8192];   // 128 KiB
    bf16_t* lds0 = &lds[0][0];

    const int tid  = threadIdx.x;
    const int lane = tid & 63;
    const int wid  = tid >> 6;
    const int wr   = wid >> 2;        // 0..1  (M half)
    const int wc   = wid & 3;         // 0..3  (N quarter)
    const int l16  = lane & 15;
    const int g    = lane >> 4;       // k-slot group 0..3
    const int sw   = l16 & 7;

    // per-lane fragment base pointers (element offsets; kh0 / kh1)
    const int offA0 = l16 * 64 + ((g ^ sw) * 8);
    const int offA1 = l16 * 64 + (((g + 4) ^ sw) * 8);
    const int offB0 = ((wc & 1) * 64 + l16) * 64 + ((g ^ sw) * 8);
    const int offB1 = ((wc & 1) * 64 + l16) * 64 + (((g + 4) ^ sw) * 8);
    const bf16_t* pak0 = lds0 + wr * 8192 + offA0;            // mat=0, half=wr
    const bf16_t* pak1 = lds0 + wr * 8192 + offA1;
    const bf16_t* pbk0 = lds0 + 16384 + (wc >> 1) * 8192 + offB0;
    const bf16_t* pbk1 = lds0 + 16384 + (wc >> 1) * 8192 + offB1;

    const int zz = blockIdx.z;
    const bf16_t* Xs = zz ? Xrb : Xb;
    const bf16_t* Ws = zz ? Wrb : Wb;
    float* S   = zz ? S_r   : S_p;
    float* SEL = zz ? SEL_r : SEL_p;

    const int m0 = blockIdx.x * BM;
    const int n0 = blockIdx.y * BN;
    const bf16_t* gA = Xs + (size_t)m0 * HH;
    const bf16_t* gB = Ws + (size_t)n0 * HH;

    f32x4 acc[8][4];
#pragma unroll
    for (int m = 0; m < 8; ++m)
#pragma unroll
        for (int n = 0; n < 4; ++n)
            acc[m][n] = (f32x4)0.0f;

    // ---- prologue: t0 full + t1 B; vmcnt(4) leaves carry = Bb1 ----
    stage_half<0, 1, 0>(lds0, gB, 0,  tid, wid);   // Bb0h0 <- t0
    stage_half<0, 1, 1>(lds0, gB, 0,  tid, wid);   // Bb0h1
    stage_half<0, 0, 0>(lds0, gA, 0,  tid, wid);   // Ab0h0
    stage_half<0, 0, 1>(lds0, gA, 0,  tid, wid);   // Ab0h1
    stage_half<1, 1, 0>(lds0, gB, 64, tid, wid);   // Bb1h0 <- t1
    stage_half<1, 1, 1>(lds0, gB, 64, tid, wid);   // Bb1h1
    VM4();
    BAR();

    // ---- main loop: 8 iterations x (2 K-tiles, 8 phases) ----
#pragma unroll 1
    for (int it = 0, te = 0; it < NKT / 2; ++it, te += 2) {
        const int k1 = ((te + 1) & (NKT - 1)) * BK;
        const int k2 = ((te + 2) & (NKT - 1)) * BK;
        const int k3 = ((te + 3) & (NKT - 1)) * BK;
        bf16x8 aq[2][2], bq[2][4];

        // P1: read B(buf0)+A(buf0,mp0); stage Ab1h0<-t+1
        read_b<0>(pbk0, pbk1, bq);
        read_a<0, 0>(pak0, pak1, aq);
        stage_half<1, 0, 0>(lds0, gA, k1, tid, wid);
        BAR(); LGKM0(); SB0();
        __builtin_amdgcn_s_setprio(1); mfma16<0>(acc, aq, bq); __builtin_amdgcn_s_setprio(0);
        BAR();
        // P2: read A(buf0,mp1); stage Ab1h1<-t+1, Bb0h0<-t+2
        read_a<0, 1>(pak0, pak1, aq);
        stage_half<1, 0, 1>(lds0, gA, k1, tid, wid);
        stage_half<0, 1, 0>(lds0, gB, k2, tid, wid);
        BAR(); LGKM0(); SB0();
        __builtin_amdgcn_s_setprio(1); mfma16<1>(acc, aq, bq); __builtin_amdgcn_s_setprio(0);
        BAR();
        // P3: read A(buf0,mp2); stage Bb0h1<-t+2
        read_a<0, 2>(pak0, pak1, aq);
        stage_half<0, 1, 1>(lds0, gB, k2, tid, wid);
        BAR(); LGKM0(); SB0();
        __builtin_amdgcn_s_setprio(1); mfma16<2>(acc, aq, bq); __builtin_amdgcn_s_setprio(0);
        BAR();
        // P4: read A(buf0,mp3); vmcnt(4)
        read_a<0, 3>(pak0, pak1, aq);
        BAR(); LGKM0(); SB0();
        __builtin_amdgcn_s_setprio(1); mfma16<3>(acc, aq, bq); __builtin_amdgcn_s_setprio(0);
        VM4(); BAR();
        // P5: read B(buf1)+A(buf1,mp0); stage Ab0h0<-t+2
        read_b<1>(pbk0, pbk1, bq);
        read_a<1, 0>(pak0, pak1, aq);
        stage_half<0, 0, 0>(lds0, gA, k2, tid, wid);
        BAR(); LGKM0(); SB0();
        __builtin_amdgcn_s_setprio(1); mfma16<0>(acc, aq, bq); __builtin_amdgcn_s_setprio(0);
        BAR();
        // P6: read A(buf1,mp1); stage Ab0h1<-t+2, Bb1h0<-t+3
        read_a<1, 1>(pak0, pak1, aq);
        stage_half<0, 0, 1>(lds0, gA, k2, tid, wid);
        stage_half<1, 1, 0>(lds0, gB, k3, tid, wid);
        BAR(); LGKM0(); SB0();
        __builtin_amdgcn_s_setprio(1); mfma16<1>(acc, aq, bq); __builtin_amdgcn_s_setprio(0);
        BAR();
        // P7: read A(buf1,mp2); stage Bb1h1<-t+3
        read_a<1, 2>(pak0, pak1, aq);
        stage_half<1, 1, 1>(lds0, gB, k3, tid, wid);
        BAR(); LGKM0(); SB0();
        __builtin_amdgcn_s_setprio(1); mfma16<2>(acc, aq, bq); __builtin_amdgcn_s_setprio(0);
        BAR();
        // P8: read A(buf1,mp3); vmcnt(4)
        read_a<1, 3>(pak0, pak1, aq);
        BAR(); LGKM0(); SB0();
        __builtin_amdgcn_s_setprio(1); mfma16<3>(acc, aq, bq); __builtin_amdgcn_s_setprio(0);
        VM4(); BAR();
    }
    asm volatile("s_waitcnt vmcnt(0) lgkmcnt(0)" ::: "memory");
    BAR();

    // ---- epilogue: exp-sum per token row + selected logit ----
#pragma unroll
    for (int m = 0; m < 8; ++m) {
#pragma unroll
        for (int j = 0; j < 4; ++j) {
            int row = m0 + wr * 128 + m * 16 + g * 4 + j;
            float s = 0.f;
#pragma unroll
            for (int n = 0; n < 4; ++n)
                s += __expf(acc[m][n][j]);
            s += __shfl_xor(s, 1, 64);
            s += __shfl_xor(s, 2, 64);
            s += __shfl_xor(s, 4, 64);
            s += __shfl_xor(s, 8, 64);
            if (l16 == 0) atomicAdd(&S[row], s);

            int id   = ids[row];
            int base = n0 + wc * 64 + l16;
#pragma unroll
            for (int n = 0; n < 4; ++n)
                if (id == base + n * 16) SEL[row] = acc[m][n][j];
        }
    }
}

// ---------------------------------------------------------------------------
// Zero S accumulators (8192 floats).
// ---------------------------------------------------------------------------
__global__ void grpo_init(float* __restrict__ p)
{
    p[blockIdx.x * 1024 + threadIdx.x] = 0.f;
}

// ---------------------------------------------------------------------------
// logp in-place over SEL: lp = SEL - log(S).
// ---------------------------------------------------------------------------
__global__ __launch_bounds__(1024)
void grpo_prep(const float* __restrict__ S_p, const float* __restrict__ S_r,
               float* __restrict__ lp_p, float* __restrict__ lp_r)
{
    int i = blockIdx.x * 1024 + threadIdx.x;
    lp_p[i] = lp_p[i] - logf(S_p[i]);
    lp_r[i] = lp_r[i] - logf(S_r[i]);
}

// ---------------------------------------------------------------------------
// Exact rank-819 threshold (k = int(4096*0.2) = 819), parallel over 64 CUs.
// ---------------------------------------------------------------------------
__global__ __launch_bounds__(64)
void grpo_thresh(const float* __restrict__ lp_r, float* __restrict__ thr)
{
    __shared__ float sh[NTOK];
    for (int i = threadIdx.x; i < NTOK; i += 64) sh[i] = lp_r[i];
    __syncthreads();
    const float v = sh[blockIdx.x * 64 + threadIdx.x];
    int lt = 0, eq = 0;
#pragma unroll 4
    for (int j = 0; j < NTOK; ++j) {
        float u = sh[j];
        lt += (u < v);
        eq += (u == v);
    }
    if (lt <= 818 && 818 < lt + eq) thr[0] = v;
}

// ---------------------------------------------------------------------------
// Final reductions -> 3 scalars. coef_1 == 1 exactly -> ppo = -adv, clip = 0.
// ---------------------------------------------------------------------------
__global__ __launch_bounds__(1024)
void grpo_final(const float* __restrict__ lp_p, const float* __restrict__ lp_r,
                const float* __restrict__ thr,
                const float* __restrict__ am, const float* __restrict__ adv,
                float* __restrict__ out)
{
    __shared__ double red[3][16];
    const int tid = threadIdx.x;
    const float t = thr[0];

    double s_loss = 0.0, s_kl = 0.0, s_am = 0.0;
    for (int i = tid; i < NTOK; i += 1024) {
        float a  = am[i];
        float pr = lp_r[i], pp = lp_p[i];
        float lr = pr - pp;
        float k3 = expf(lr) - lr - 1.0f;
        float kl = (pr <= t) ? k3 * 5.0f : 0.0f;
        float ad = adv[i / TT];
        float ptl = -ad + 0.04f * kl;
        s_loss += (double)(ptl * a);
        s_kl   += (double)(kl * a);
        s_am   += (double)a;
    }
#pragma unroll
    for (int off = 32; off; off >>= 1) {
        s_loss += __shfl_down(s_loss, off, 64);
        s_kl   += __shfl_down(s_kl,   off, 64);
        s_am   += __shfl_down(s_am,   off, 64);
    }
    const int wid = tid >> 6;
    if ((tid & 63) == 0) { red[0][wid] = s_loss; red[1][wid] = s_kl; red[2][wid] = s_am; }
    __syncthreads();
    if (tid == 0) {
        double L = 0, K = 0, A = 0;
        for (int w = 0; w < 16; ++w) { L += red[0][w]; K += red[1][w]; A += red[2][w]; }
        double norm = A < 1.0 ? 1.0 : A;
        out[0] = (float)(L / norm);
        out[1] = (float)(K / norm);
        out[2] = 0.0f;
    }
}

extern "C" void kernel_launch(void* const* d_in, const int* in_sizes, int n_in,
                              void* d_out, int out_size, void* d_ws, size_t ws_size,
                              hipStream_t stream)
{
    const float* X   = (const float*)d_in[0];
    const float* W   = (const float*)d_in[1];
    const int*   ids = (const int*)  d_in[2];
    const float* am  = (const float*)d_in[3];
    const float* adv = (const float*)d_in[4];
    const float* Xr  = (const float*)d_in[5];
    const float* Wr  = (const float*)d_in[6];
    float* out = (float*)d_out;

    float* S_p  = (float*)d_ws;
    float* S_r  = S_p + NTOK;
    float* lp_p = S_r + NTOK;      // SEL_p, overwritten in-place by prep
    float* lp_r = lp_p + NTOK;     // SEL_r
    float* thr  = S_p;             // reused after S consumed

    const size_t bf16_off = 65536;
    const size_t nX = (size_t)NTOK * HH, nW = (size_t)VV * HH;

    bf16_t* Xb  = (bf16_t*)((char*)d_ws + bf16_off);
    bf16_t* Wb  = Xb + nX;
    bf16_t* Xrb = Wb + nW;
    bf16_t* Wrb = Xrb + nX;

    hipLaunchKernelGGL(grpo_init, dim3(8), dim3(1024), 0, stream, S_p);

    hipLaunchKernelGGL(grpo_cvt_all, dim3(4096), dim3(256), 0, stream,
                       X, W, Xr, Wr, Xb, Wb, Xrb, Wrb);

    dim3 grid(NTOK / BM, VV / BN, 2);   // m fastest; z = policy/ref
    hipLaunchKernelGGL(grpo_gemm_t, grid, dim3(512), 0, stream,
                       Xb, Wb, Xrb, Wrb, ids, S_p, lp_p, S_r, lp_r);

    hipLaunchKernelGGL(grpo_prep,   dim3(4),  dim3(1024), 0, stream, S_p, S_r, lp_p, lp_r);
    hipLaunchKernelGGL(grpo_thresh, dim3(64), dim3(64),   0, stream, lp_r, thr);
    hipLaunchKernelGGL(grpo_final,  dim3(1),  dim3(1024), 0, stream, lp_p, lp_r, thr, am, adv, out);
}

// Round 10
// 691.180 us; speedup vs baseline: 1.8381x; 1.2096x over previous
//
#include <hip/hip_runtime.h>
#include <hip/hip_bf16.h>
#include <hip/hip_fp8.h>

typedef float f32x4  __attribute__((ext_vector_type(4)));
typedef float f32x16 __attribute__((ext_vector_type(16)));
typedef int   i32x4  __attribute__((ext_vector_type(4)));
typedef int   i32x8  __attribute__((ext_vector_type(8)));

#define NTOK 4096   // B*T
#define TT   512
#define HH   1024
#define VV   32000

#define BM   128
#define BN   256
#define NKT  16     // K-tiles of 64

#define SC1  0x7F7F7F7F          // e8m0 = 127 (2^0) in every byte
#define INVS 0.000244140625f     // 1/4096 undoes the 64*64 pre-scale

#define GLOBAL_AS(p) ((const __attribute__((address_space(1))) void*)(const void*)(p))
#define LDS_AS(p)    ((__attribute__((address_space(3))) void*)(void*)(p))
#define BAR()   asm volatile("s_barrier" ::: "memory")
#define LGKM0() asm volatile("s_waitcnt lgkmcnt(0)" ::: "memory")
#define VM3()   asm volatile("s_waitcnt vmcnt(3)" ::: "memory")
#define SB0()   __builtin_amdgcn_sched_barrier(0)

// ---------------------------------------------------------------------------
// f32 -> e4m3 (x64 uniform pre-scale), all four tensors, one dispatch.
// ---------------------------------------------------------------------------
__global__ __launch_bounds__(256)
void grpo_cvt_all(const float* __restrict__ X,  const float* __restrict__ W,
                  const float* __restrict__ Xr, const float* __restrict__ Wr,
                  unsigned char* __restrict__ Xq,  unsigned char* __restrict__ Wq,
                  unsigned char* __restrict__ Xrq, unsigned char* __restrict__ Wrq)
{
    const int nX8 = NTOK * HH / 8, nW8 = VV * HH / 8;
    const int b1 = nX8, b2 = nX8 + nW8, b3 = b2 + nX8;
    const int total = 2 * (nX8 + nW8);
    const int stride = gridDim.x * 256;
    for (int i = blockIdx.x * 256 + threadIdx.x; i < total; i += stride) {
        const float* s; unsigned char* d; int j;
        if      (i < b1) { s = X;  d = Xq;  j = i; }
        else if (i < b2) { s = W;  d = Wq;  j = i - b1; }
        else if (i < b3) { s = Xr; d = Xrq; j = i - b2; }
        else             { s = Wr; d = Wrq; j = i - b3; }
        f32x4 v0 = *(const f32x4*)(s + (size_t)j * 8);
        f32x4 v1 = *(const f32x4*)(s + (size_t)j * 8 + 4);
        union { unsigned char b[8]; unsigned long long u; } r;
#pragma unroll
        for (int e = 0; e < 4; ++e) r.b[e]     = __hip_fp8_e4m3(v0[e] * 64.0f).__x;
#pragma unroll
        for (int e = 0; e < 4; ++e) r.b[4 + e] = __hip_fp8_e4m3(v1[e] * 64.0f).__x;
        *(unsigned long long*)(d + (size_t)j * 8) = r.u;
    }
}

// ---------------------------------------------------------------------------
// MX-fp8 GEMM: 128x256 tile, BK=64, mfma_scale 32x32x64 (uniform scales=1.0),
// 8 waves of 64x64, 48 KB LDS ring -> 2 blocks/CU. z-merged policy/ref.
// LDS: [buf][A 8KB][B 16KB], buf stride 24576 B. Rows = 64 B (4 x 16B slots).
// Swizzle: phys slot = logical ^ ((row>>1)&3) (involution; even bank spread).
// Phase t: read 8 x b128 (A mi0/1, B ni0/1) from buf=t&1; LGKM0+BAR (cross-
// wave WAR); stage tile t+2 into same buf (3 gloads); SB0; 4 MFMA (setprio);
// vmcnt(3) drains tile t+1; BAR. Prologue stages t0,t1; vmcnt(3)=t0 landed.
// Logits come out x4096; epilogue multiplies by 1/4096 (exact).
// ---------------------------------------------------------------------------
__global__ __launch_bounds__(512, 4)
void grpo_gemm_f8(const unsigned char* __restrict__ Xq,  const unsigned char* __restrict__ Wq,
                  const unsigned char* __restrict__ Xrq, const unsigned char* __restrict__ Wrq,
                  const int* __restrict__ ids,
                  float* __restrict__ S_p, float* __restrict__ SEL_p,
                  float* __restrict__ S_r, float* __restrict__ SEL_r)
{
    __shared__ int ldsw[12288];   // 48 KiB
    const int tid  = threadIdx.x;
    const int lane = tid & 63;
    const int wid  = tid >> 6;
    const int wr   = wid >> 2;        // 0..1 (M split: 2 x 64)
    const int wc   = wid & 3;         // 0..3 (N split: 4 x 64)
    const int l31  = lane & 31;
    const int hi   = lane >> 5;
    const int swz  = (l31 >> 1) & 3;
    const int s0   = ((2 * hi)     ^ swz) * 4;   // int offsets within 64B row
    const int s1   = ((2 * hi + 1) ^ swz) * 4;

    const int zz = blockIdx.z;
    const unsigned char* Xs = zz ? Xrq : Xq;
    const unsigned char* Ws = zz ? Wrq : Wq;
    float* S   = zz ? S_r   : S_p;
    float* SEL = zz ? SEL_r : SEL_p;

    const int m0 = blockIdx.x * BM;
    const int n0 = blockIdx.y * BN;

    // fragment row bases (int offsets; row = 16 ints). mi/ni=1 adds 512.
    const int arow0 = (wr * 64 + l31) * 16;
    const int brow0 = (wc * 64 + l31) * 16;

    // staging: A = 512 chunks (1/thread), B = 1024 chunks (2/thread)
    const int aRow  = tid >> 2;
    const int aSlot = ((tid & 3) ^ ((tid >> 3) & 3)) * 16;   // inverse swizzle, bytes
    const unsigned char* gAb  = Xs + (size_t)(m0 + aRow) * HH + aSlot;
    const unsigned char* gBb0 = Ws + (size_t)(n0 + aRow) * HH + aSlot;
    const unsigned char* gBb1 = Ws + (size_t)(n0 + 128 + aRow) * HH + aSlot;
    char* ldsc = (char*)ldsw;
    char* dA   = ldsc + wid * 1024;            // + buf*24576
    char* dB0  = ldsc + 8192 + wid * 1024;
    char* dB1  = ldsc + 16384 + wid * 1024;

#define STAGE(BOFF, KC)                                                             \
    do {                                                                            \
        __builtin_amdgcn_global_load_lds(GLOBAL_AS(gAb  + (KC)), LDS_AS(dA  + (BOFF)), 16, 0, 0); \
        __builtin_amdgcn_global_load_lds(GLOBAL_AS(gBb0 + (KC)), LDS_AS(dB0 + (BOFF)), 16, 0, 0); \
        __builtin_amdgcn_global_load_lds(GLOBAL_AS(gBb1 + (KC)), LDS_AS(dB1 + (BOFF)), 16, 0, 0); \
    } while (0)

    f32x16 acc[2][2];
#pragma unroll
    for (int mi = 0; mi < 2; ++mi)
#pragma unroll
        for (int ni = 0; ni < 2; ++ni)
            acc[mi][ni] = (f32x16)0.0f;

    // ---- prologue ----
    STAGE(0, 0);
    STAGE(24576, 64);
    VM3();
    BAR();

#define F8_BODY(BOFF, TNEXT)                                                        \
    {                                                                               \
        const int ab = (BOFF) / 4;                                                  \
        const int bb = (BOFF) / 4 + 2048;                                           \
        i32x4 a0l = *(const i32x4*)(ldsw + ab + arow0 + s0);                        \
        i32x4 a0h = *(const i32x4*)(ldsw + ab + arow0 + s1);                        \
        i32x4 a1l = *(const i32x4*)(ldsw + ab + arow0 + 512 + s0);                  \
        i32x4 a1h = *(const i32x4*)(ldsw + ab + arow0 + 512 + s1);                  \
        i32x4 b0l = *(const i32x4*)(ldsw + bb + brow0 + s0);                        \
        i32x4 b0h = *(const i32x4*)(ldsw + bb + brow0 + s1);                        \
        i32x4 b1l = *(const i32x4*)(ldsw + bb + brow0 + 512 + s0);                  \
        i32x4 b1h = *(const i32x4*)(ldsw + bb + brow0 + 512 + s1);                  \
        i32x8 a0 = __builtin_shufflevector(a0l, a0h, 0, 1, 2, 3, 4, 5, 6, 7);       \
        i32x8 a1 = __builtin_shufflevector(a1l, a1h, 0, 1, 2, 3, 4, 5, 6, 7);       \
        i32x8 b0 = __builtin_shufflevector(b0l, b0h, 0, 1, 2, 3, 4, 5, 6, 7);       \
        i32x8 b1 = __builtin_shufflevector(b1l, b1h, 0, 1, 2, 3, 4, 5, 6, 7);       \
        LGKM0(); BAR();                                                             \
        STAGE((((TNEXT) & 1) * 24576), (((TNEXT) & (NKT - 1)) * 64));               \
        SB0();                                                                      \
        __builtin_amdgcn_s_setprio(1);                                              \
        acc[0][0] = __builtin_amdgcn_mfma_scale_f32_32x32x64_f8f6f4(a0, b0, acc[0][0], 0, 0, 0, SC1, 0, SC1); \
        acc[0][1] = __builtin_amdgcn_mfma_scale_f32_32x32x64_f8f6f4(a0, b1, acc[0][1], 0, 0, 0, SC1, 0, SC1); \
        acc[1][0] = __builtin_amdgcn_mfma_scale_f32_32x32x64_f8f6f4(a1, b0, acc[1][0], 0, 0, 0, SC1, 0, SC1); \
        acc[1][1] = __builtin_amdgcn_mfma_scale_f32_32x32x64_f8f6f4(a1, b1, acc[1][1], 0, 0, 0, SC1, 0, SC1); \
        __builtin_amdgcn_s_setprio(0);                                              \
        VM3(); BAR();                                                               \
    }

    // ---- main loop: 16 K-tiles, double-buffered ----
#pragma unroll 1
    for (int t = 0; t < NKT; t += 2) {
        F8_BODY(0,     t + 2);   // read buf0 (tile t),   stage tile t+2 -> buf0
        F8_BODY(24576, t + 3);   // read buf1 (tile t+1), stage tile t+3 -> buf1
    }

    // ---- epilogue: exp-sum per token row + selected logit ----
    // 32x32 C/D: col = lane&31, row = (rg&3) + 8*(rg>>2) + 4*(lane>>5)
#pragma unroll
    for (int mi = 0; mi < 2; ++mi) {
#pragma unroll
        for (int rg = 0; rg < 16; ++rg) {
            const int row = m0 + wr * 64 + mi * 32 + (rg & 3) + 8 * (rg >> 2) + 4 * hi;
            const float v0 = acc[mi][0][rg] * INVS;
            const float v1 = acc[mi][1][rg] * INVS;
            float s = __expf(v0) + __expf(v1);
            s += __shfl_xor(s, 1, 64);
            s += __shfl_xor(s, 2, 64);
            s += __shfl_xor(s, 4, 64);
            s += __shfl_xor(s, 8, 64);
            s += __shfl_xor(s, 16, 64);
            if (l31 == 0) atomicAdd(&S[row], s);

            const int id = ids[row];
            const int c0 = n0 + wc * 64 + l31;
            if (id == c0)      SEL[row] = v0;
            if (id == c0 + 32) SEL[row] = v1;
        }
    }
#undef F8_BODY
#undef STAGE
}

// ---------------------------------------------------------------------------
// Zero S accumulators (8192 floats).
// ---------------------------------------------------------------------------
__global__ void grpo_init(float* __restrict__ p)
{
    p[blockIdx.x * 1024 + threadIdx.x] = 0.f;
}

// ---------------------------------------------------------------------------
// logp in-place over SEL: lp = SEL - log(S).
// ---------------------------------------------------------------------------
__global__ __launch_bounds__(1024)
void grpo_prep(const float* __restrict__ S_p, const float* __restrict__ S_r,
               float* __restrict__ lp_p, float* __restrict__ lp_r)
{
    int i = blockIdx.x * 1024 + threadIdx.x;
    lp_p[i] = lp_p[i] - logf(S_p[i]);
    lp_r[i] = lp_r[i] - logf(S_r[i]);
}

// ---------------------------------------------------------------------------
// Exact rank-819 threshold (k = int(4096*0.2) = 819), parallel over 64 CUs.
// ---------------------------------------------------------------------------
__global__ __launch_bounds__(64)
void grpo_thresh(const float* __restrict__ lp_r, float* __restrict__ thr)
{
    __shared__ float sh[NTOK];
    for (int i = threadIdx.x; i < NTOK; i += 64) sh[i] = lp_r[i];
    __syncthreads();
    const float v = sh[blockIdx.x * 64 + threadIdx.x];
    int lt = 0, eq = 0;
#pragma unroll 4
    for (int j = 0; j < NTOK; ++j) {
        float u = sh[j];
        lt += (u < v);
        eq += (u == v);
    }
    if (lt <= 818 && 818 < lt + eq) thr[0] = v;
}

// ---------------------------------------------------------------------------
// Final reductions -> 3 scalars. coef_1 == 1 exactly -> ppo = -adv, clip = 0.
// ---------------------------------------------------------------------------
__global__ __launch_bounds__(1024)
void grpo_final(const float* __restrict__ lp_p, const float* __restrict__ lp_r,
                const float* __restrict__ thr,
                const float* __restrict__ am, const float* __restrict__ adv,
                float* __restrict__ out)
{
    __shared__ double red[3][16];
    const int tid = threadIdx.x;
    const float t = thr[0];

    double s_loss = 0.0, s_kl = 0.0, s_am = 0.0;
    for (int i = tid; i < NTOK; i += 1024) {
        float a  = am[i];
        float pr = lp_r[i], pp = lp_p[i];
        float lr = pr - pp;
        float k3 = expf(lr) - lr - 1.0f;
        float kl = (pr <= t) ? k3 * 5.0f : 0.0f;
        float ad = adv[i / TT];
        float ptl = -ad + 0.04f * kl;
        s_loss += (double)(ptl * a);
        s_kl   += (double)(kl * a);
        s_am   += (double)a;
    }
#pragma unroll
    for (int off = 32; off; off >>= 1) {
        s_loss += __shfl_down(s_loss, off, 64);
        s_kl   += __shfl_down(s_kl,   off, 64);
        s_am   += __shfl_down(s_am,   off, 64);
    }
    const int wid = tid >> 6;
    if ((tid & 63) == 0) { red[0][wid] = s_loss; red[1][wid] = s_kl; red[2][wid] = s_am; }
    __syncthreads();
    if (tid == 0) {
        double L = 0, K = 0, A = 0;
        for (int w = 0; w < 16; ++w) { L += red[0][w]; K += red[1][w]; A += red[2][w]; }
        double norm = A < 1.0 ? 1.0 : A;
        out[0] = (float)(L / norm);
        out[1] = (float)(K / norm);
        out[2] = 0.0f;
    }
}

extern "C" void kernel_launch(void* const* d_in, const int* in_sizes, int n_in,
                              void* d_out, int out_size, void* d_ws, size_t ws_size,
                              hipStream_t stream)
{
    const float* X   = (const float*)d_in[0];
    const float* W   = (const float*)d_in[1];
    const int*   ids = (const int*)  d_in[2];
    const float* am  = (const float*)d_in[3];
    const float* adv = (const float*)d_in[4];
    const float* Xr  = (const float*)d_in[5];
    const float* Wr  = (const float*)d_in[6];
    float* out = (float*)d_out;

    float* S_p  = (float*)d_ws;
    float* S_r  = S_p + NTOK;
    float* lp_p = S_r + NTOK;      // SEL_p, overwritten in-place by prep
    float* lp_r = lp_p + NTOK;     // SEL_r
    float* thr  = S_p;             // reused after S consumed

    const size_t q_off = 65536;
    const size_t nX = (size_t)NTOK * HH, nW = (size_t)VV * HH;

    unsigned char* Xq  = (unsigned char*)d_ws + q_off;
    unsigned char* Wq  = Xq + nX;
    unsigned char* Xrq = Wq + nW;
    unsigned char* Wrq = Xrq + nX;

    hipLaunchKernelGGL(grpo_init, dim3(8), dim3(1024), 0, stream, S_p);

    hipLaunchKernelGGL(grpo_cvt_all, dim3(4096), dim3(256), 0, stream,
                       X, W, Xr, Wr, Xq, Wq, Xrq, Wrq);

    dim3 grid(NTOK / BM, VV / BN, 2);   // 32 x 125 x 2; m fastest
    hipLaunchKernelGGL(grpo_gemm_f8, grid, dim3(512), 0, stream,
                       Xq, Wq, Xrq, Wrq, ids, S_p, lp_p, S_r, lp_r);

    hipLaunchKernelGGL(grpo_prep,   dim3(4),  dim3(1024), 0, stream, S_p, S_r, lp_p, lp_r);
    hipLaunchKernelGGL(grpo_thresh, dim3(64), dim3(64),   0, stream, lp_r, thr);
    hipLaunchKernelGGL(grpo_final,  dim3(1),  dim3(1024), 0, stream, lp_p, lp_r, thr, am, adv, out);
}